// Round 4
// baseline (905.812 us; speedup 1.0000x reference)
//
#include <hip/hip_runtime.h>
#include <hip/hip_bf16.h>
#include <math.h>

// B=4, S=4096, D=256, T=256, K_PATCH=8. fp32 I/O (confirmed by npz sizes / NaN forensics).
// Internal: weights staged as transposed bf16 (ws = 1.06 MB, proven safe), fp32 accumulate.
#define S_   4096
#define XROW 259

typedef const float* fpp;

__device__ __forceinline__ float us2f(unsigned short u){ return __uint_as_float(((unsigned)u)<<16); }
__device__ __forceinline__ unsigned short f2bu(float f){
  __hip_bfloat16 h = __float2bfloat16(f);
  return *reinterpret_cast<unsigned short*>(&h);
}
__device__ __forceinline__ float gelu_f(float v){ return 0.5f*v*(1.0f+erff(v*0.70710678118654752f)); }

// ---------- weight prep: fp32 -> transposed bf16 WT[j*256+k]; Wqk = Wq-Wk ----------
__global__ __launch_bounds__(256) void k_prep(
    fpp W_in, fpp Wq, fpp Wk, fpp Wv, fpp Wg1, fpp Wg2, fpp W_out, fpp Wp2,
    unsigned short* __restrict__ Wb, unsigned short* __restrict__ Wp2b)
{
  int e = blockIdx.x*256 + threadIdx.x;            // e < 65536
  int k = e >> 8, j = e & 255, d = j*256 + k;
  Wb[         d] = f2bu(W_in[e]);
  Wb[ 65536 + d] = f2bu(Wq[e] - Wk[e]);
  Wb[131072 + d] = f2bu(Wv[e]);
  Wb[196608 + d] = f2bu(Wg1[e]);
  Wb[262144 + d] = f2bu(Wg2[e]);
  Wb[327680 + d] = f2bu(W_out[e]);
  if (e < 32768) {                                 // Wp2 (128,256) -> Wp2b[j*128+k]
    int k2 = e >> 8, j2 = e & 255;
    Wp2b[j2*128 + k2] = f2bu(Wp2[e]);
  }
}

// ---------- kNN: top-8 smallest dist per row, stable tie order ----------
// 256 blocks; block = 64 rows (one per lane), 4 waves split the 4096-candidate scan.
__global__ __launch_bounds__(256) void k_knn(fpp x, unsigned short* __restrict__ idxw)
{
  __shared__ float cxa[S_], cya[S_], cza[S_];      // 48 KiB
  int b = blockIdx.x >> 6;
  int rowbase = (blockIdx.x & 63) * 64;
  fpp xb = x + (size_t)b*S_*XROW;
  for (int t = threadIdx.x; t < S_; t += 256) {
    cxa[t] = xb[t*XROW+0];
    cya[t] = xb[t*XROW+1];
    cza[t] = xb[t*XROW+2];
  }
  __syncthreads();
  int lane = threadIdx.x & 63;
  int wave = threadIdx.x >> 6;
  int s = rowbase + lane;
  float sx = cxa[s], sy = cya[s], sz = cza[s];
  float sq = fmaf(sz, sz, fmaf(sy, sy, sx*sx));
  float bd[8]; int bi[8];
#pragma unroll
  for (int i=0;i<8;i++){ bd[i]=INFINITY; bi[i]=0; }
  int t0 = wave*1024;
  for (int t = t0; t < t0+1024; ++t) {
    float tx = cxa[t], ty = cya[t], tz = cza[t];   // uniform addr -> LDS broadcast
    float tq = fmaf(tz, tz, fmaf(ty, ty, tx*tx));
    float dt = fmaf(sz, tz, fmaf(sy, ty, sx*tx));
    float d  = sq + tq - 2.0f*dt;
    if (d < bd[7]) {                               // strict < => stable tie order
      float dd=d; int ii=t;
#pragma unroll
      for (int i=0;i<8;i++){
        if (dd < bd[i]) { float tf=bd[i]; bd[i]=dd; dd=tf; int ti=bi[i]; bi[i]=ii; ii=ti; }
      }
    }
  }
  __syncthreads();                                 // reuse cxa/cya as merge scratch
  float* mf = cxa;
  int*   mi = (int*)cya;
  if (wave > 0) {
#pragma unroll
    for (int i=0;i<8;i++){ mf[((wave-1)*64+lane)*8+i]=bd[i]; mi[((wave-1)*64+lane)*8+i]=bi[i]; }
  }
  __syncthreads();
  if (wave == 0) {
    for (int w=0; w<3; ++w){
#pragma unroll
      for (int i=0;i<8;i++){
        float d = mf[(w*64+lane)*8+i]; int tt = mi[(w*64+lane)*8+i];
        if (d < bd[7]) {
          float dd=d; int ii=tt;
#pragma unroll
          for (int q=0;q<8;q++){
            if (dd < bd[q]) { float tf=bd[q]; bd[q]=dd; dd=tf; int ti=bi[q]; bi[q]=ii; ii=ti; }
          }
        }
      }
    }
#pragma unroll
    for (int i=0;i<8;i++) idxw[((size_t)(b*S_ + s))*8 + i] = (unsigned short)bi[i];
  }
}

// ---------- fused GEMM helper: acc[m] = sum_k Xt[m][k]*Wrow[j*256+k], bf16 weights ----------
__device__ __forceinline__ void gemm16(const float (*Xt)[260], const unsigned short* Wrow,
                                       int j, float* acc)
{
#pragma unroll
  for (int m=0;m<16;m++) acc[m]=0.f;
  for (int kc=0; kc<32; ++kc) {
    uint4 q = *(const uint4*)(Wrow + (size_t)j*256 + kc*8);
    float w0=__uint_as_float(q.x<<16), w1=__uint_as_float(q.x&0xffff0000u);
    float w2=__uint_as_float(q.y<<16), w3=__uint_as_float(q.y&0xffff0000u);
    float w4=__uint_as_float(q.z<<16), w5=__uint_as_float(q.z&0xffff0000u);
    float w6=__uint_as_float(q.w<<16), w7=__uint_as_float(q.w&0xffff0000u);
#pragma unroll
    for (int m=0;m<16;m++){
      const float4* xr = (const float4*)&Xt[m][kc*8];   // uniform addr -> broadcast
      float4 a = xr[0], bq = xr[1];
      acc[m]=fmaf(a.x ,w0,acc[m]); acc[m]=fmaf(a.y ,w1,acc[m]);
      acc[m]=fmaf(a.z ,w2,acc[m]); acc[m]=fmaf(a.w ,w3,acc[m]);
      acc[m]=fmaf(bq.x,w4,acc[m]); acc[m]=fmaf(bq.y,w5,acc[m]);
      acc[m]=fmaf(bq.z,w6,acc[m]); acc[m]=fmaf(bq.w,w7,acc[m]);
    }
  }
}

// ---------- megakernel: posMLP + 6 fused GEMMs + softmax, 16 tokens/block ----------
__global__ __launch_bounds__(256) void k_mega(
    fpp x, const unsigned short* __restrict__ idxw,
    fpp Wp1, fpp bp1, const unsigned short* __restrict__ Wp2b, fpp bp2,
    const unsigned short* __restrict__ Wb,
    fpp b_in, fpp bg1, fpp bg2, fpp b_out,
    float* __restrict__ out)
{
  __shared__ __align__(16) char pool[33280];        // T1|T2  unioned with  hh|w1|b1s
  __shared__ __align__(8)  unsigned short pe[16][256];
  float (*T1)[260] = (float (*)[260])pool;                       // 16x260 f32
  float (*T2)[260] = (float (*)[260])(pool + 16640);
  unsigned short (*hh)[136] = (unsigned short (*)[136])pool;     // 64x136 bf16 (17408 B)
  float* w1f = (float*)(pool + 17408);                           // 10x128 f32
  float* b1f = w1f + 1280;                                       // 128 f32 (ends 23040)

  const int tid  = threadIdx.x;
  const int tok0 = blockIdx.x * 16;                 // global token base
  const int b    = tok0 >> 12;
  const int j    = tid;

  for (int i = tid; i < 1280; i += 256) w1f[i] = Wp1[i];
  if (tid < 128) b1f[tid] = bp1[tid];
  __syncthreads();

  float bp2j = bp2[j];

  // ---- phase 0: posMLP, 2 chunks x 64 rows (8 tokens x 8 neighbors) ----
  for (int c = 0; c < 2; ++c) {
    { // layer 1: 4 threads/row, each 32 cols (stride-4 interleave)
      int r = tid >> 2, q = tid & 3;
      int mtok = c*8 + (r >> 3), kn = r & 7;
      size_t grow = (size_t)(tok0 + mtok);
      size_t xrow = grow * XROW;
      float cx=x[xrow], cy=x[xrow+1], cz=x[xrow+2];
      int nb = idxw[grow*8 + kn];
      size_t nrow = ((size_t)(b*S_ + nb)) * XROW;
      float nx=x[nrow], ny=x[nrow+1], nz=x[nrow+2];
      float rx=nx-cx, ry=ny-cy, rz=nz-cz;
      float nrm = sqrtf(fmaf(rz,rz,fmaf(ry,ry,rx*rx)));
      float ps[10] = {cx,cy,cz,nx,ny,nz,rx,ry,rz,nrm};
      for (int cc=0; cc<32; ++cc) {
        int col = cc*4 + q;
        float a = b1f[col];
#pragma unroll
        for (int d2=0; d2<10; ++d2) a = fmaf(ps[d2], w1f[d2*128+col], a);
        hh[r][col] = f2bu(gelu_f(a));
      }
    }
    __syncthreads();
    { // layer 2 + max over neighbors -> pe
      float acc[64];
#pragma unroll
      for (int i=0;i<64;i++) acc[i]=0.f;
      for (int kc=0; kc<32; ++kc) {
        ushort4 wq = *(const ushort4*)(Wp2b + (size_t)j*128 + kc*4);
        float w0=us2f(wq.x), w1v=us2f(wq.y), w2=us2f(wq.z), w3=us2f(wq.w);
#pragma unroll
        for (int r=0;r<64;++r){
          ushort4 hv = *(const ushort4*)&hh[r][kc*4];  // uniform addr -> broadcast
          acc[r]=fmaf(us2f(hv.x),w0,acc[r]);
          acc[r]=fmaf(us2f(hv.y),w1v,acc[r]);
          acc[r]=fmaf(us2f(hv.z),w2,acc[r]);
          acc[r]=fmaf(us2f(hv.w),w3,acc[r]);
        }
      }
#pragma unroll
      for (int m8=0;m8<8;m8++){
        float mx = acc[m8*8];
#pragma unroll
        for (int k=1;k<8;k++) mx = fmaxf(mx, acc[m8*8+k]);
        pe[c*8+m8][j] = f2bu(mx + bp2j);
      }
    }
    __syncthreads();
  }

  // ---- stage pre -> T1 (fp32) ----
  for (int i = tid; i < 4096; i += 256) {
    int r = i >> 8, cc = i & 255;
    T1[r][cc] = x[(size_t)(tok0 + r)*XROW + 3 + cc];
  }
  __syncthreads();

  float acc[16];

  // ---- h = pre @ W_in + b_in + pos_emb -> T2 ----
  gemm16(T1, Wb + 0, j, acc);
  {
    float binj = b_in[j];
#pragma unroll
    for (int m=0;m<16;m++) T2[m][j] = acc[m] + binj + us2f(pe[m][j]);
  }
  __syncthreads();

  // ---- g = h @ (Wq-Wk) -> T1 (pre dead) ----
  gemm16(T2, Wb + 65536, j, acc);
#pragma unroll
  for (int m=0;m<16;m++) T1[m][j] = acc[m];
  __syncthreads();

  // ---- a1 = gelu(g @ Wg1 + bg1) -> T1 in place ----
  gemm16(T1, Wb + 196608, j, acc);
  __syncthreads();
  {
    float bg1j = bg1[j];
#pragma unroll
    for (int m=0;m<16;m++) T1[m][j] = gelu_f(acc[m] + bg1j);
  }
  __syncthreads();

  // ---- a2 = (a1 @ Wg2 + bg2) * scale -> T1 in place ----
  gemm16(T1, Wb + 262144, j, acc);
  __syncthreads();
  {
    float bg2j = bg2[j];
#pragma unroll
    for (int m=0;m<16;m++) T1[m][j] = (acc[m] + bg2j) * 0.0625f;
  }
  __syncthreads();

  // ---- softmax over channels, in T1; 4 rows/wave, 16 lanes/row ----
  {
    int lane = tid & 63, wv = tid >> 6;
    int row = wv*4 + (lane >> 4), li = lane & 15;
    float4* rp = (float4*)&T1[row][li*16];
    float4 v0=rp[0], v1=rp[1], v2=rp[2], v3=rp[3];
    float mx = fmaxf(fmaxf(fmaxf(v0.x,v0.y),fmaxf(v0.z,v0.w)),
                     fmaxf(fmaxf(v1.x,v1.y),fmaxf(v1.z,v1.w)));
    mx = fmaxf(mx, fmaxf(fmaxf(fmaxf(v2.x,v2.y),fmaxf(v2.z,v2.w)),
                         fmaxf(fmaxf(v3.x,v3.y),fmaxf(v3.z,v3.w))));
#pragma unroll
    for (int o=1;o<16;o<<=1) mx = fmaxf(mx, __shfl_xor(mx, o));
    v0.x=expf(v0.x-mx); v0.y=expf(v0.y-mx); v0.z=expf(v0.z-mx); v0.w=expf(v0.w-mx);
    v1.x=expf(v1.x-mx); v1.y=expf(v1.y-mx); v1.z=expf(v1.z-mx); v1.w=expf(v1.w-mx);
    v2.x=expf(v2.x-mx); v2.y=expf(v2.y-mx); v2.z=expf(v2.z-mx); v2.w=expf(v2.w-mx);
    v3.x=expf(v3.x-mx); v3.y=expf(v3.y-mx); v3.z=expf(v3.z-mx); v3.w=expf(v3.w-mx);
    float ssum = (v0.x+v0.y+v0.z+v0.w)+(v1.x+v1.y+v1.z+v1.w)
               + (v2.x+v2.y+v2.z+v2.w)+(v3.x+v3.y+v3.z+v3.w);
#pragma unroll
    for (int o=1;o<16;o<<=1) ssum += __shfl_xor(ssum, o);
    float inv = 1.0f/ssum;
    v0.x*=inv; v0.y*=inv; v0.z*=inv; v0.w*=inv;
    v1.x*=inv; v1.y*=inv; v1.z*=inv; v1.w*=inv;
    v2.x*=inv; v2.y*=inv; v2.z*=inv; v2.w*=inv;
    v3.x*=inv; v3.y*=inv; v3.z*=inv; v3.w*=inv;
    rp[0]=v0; rp[1]=v1; rp[2]=v2; rp[3]=v3;
  }
  __syncthreads();

  // ---- v = h @ Wv ; r = attn * v -> T1 ----
  gemm16(T2, Wb + 131072, j, acc);
  {
    float rr[16];
#pragma unroll
    for (int m=0;m<16;m++) rr[m] = T1[m][j] * acc[m];
    __syncthreads();
#pragma unroll
    for (int m=0;m<16;m++) T1[m][j] = rr[m];
  }
  __syncthreads();

  // ---- out = r @ W_out + b_out + pre ----
  gemm16(T1, Wb + 327680, j, acc);
  {
    float boj = b_out[j];
#pragma unroll
    for (int m=0;m<16;m++){
      size_t row = (size_t)(tok0 + m);
      out[row*256 + j] = acc[m] + boj + x[row*XROW + 3 + j];
    }
  }
}

extern "C" void kernel_launch(void* const* d_in, const int* in_sizes, int n_in,
                              void* d_out, int out_size, void* d_ws, size_t ws_size,
                              hipStream_t stream)
{
  fpp x    = (fpp)d_in[0];
  fpp W_in = (fpp)d_in[1];  fpp b_in = (fpp)d_in[2];
  fpp Wq   = (fpp)d_in[3];  fpp Wk   = (fpp)d_in[4];  fpp Wv = (fpp)d_in[5];
  fpp Wg1  = (fpp)d_in[6];  fpp bg1  = (fpp)d_in[7];
  fpp Wg2  = (fpp)d_in[8];  fpp bg2  = (fpp)d_in[9];
  fpp W_out= (fpp)d_in[10]; fpp b_out= (fpp)d_in[11];
  fpp Wp1  = (fpp)d_in[12]; fpp bp1  = (fpp)d_in[13];
  fpp Wp2  = (fpp)d_in[14]; fpp bp2  = (fpp)d_in[15];

  // ---- workspace: 1,114,112 bytes total (proven safe in round 3) ----
  char* ws = (char*)d_ws;
  unsigned short* idxw = (unsigned short*)ws;            // 131072 u16 = 262144 B
  unsigned short* Wb   = (unsigned short*)(ws + 262144); // 6x65536 u16 = 786432 B
  unsigned short* Wp2b = (unsigned short*)(ws + 1048576);// 32768 u16 = 65536 B

  k_prep<<<256, 256, 0, stream>>>(W_in,Wq,Wk,Wv,Wg1,Wg2,W_out,Wp2, Wb, Wp2b);
  k_knn <<<256, 256, 0, stream>>>(x, idxw);
  k_mega<<<1024,256, 0, stream>>>(x, idxw, Wp1, bp1, Wp2b, bp2, Wb,
                                  b_in, bg1, bg2, b_out, (float*)d_out);
}

// Round 5
// 350.138 us; speedup vs baseline: 2.5870x; 2.5870x over previous
//
#include <hip/hip_runtime.h>
#include <hip/hip_bf16.h>
#include <math.h>

// B=4, S=4096, D=256, T=256, K_PATCH=8. fp32 I/O, bf16 MFMA compute, fp32 accum.
// ws = 1.09 MB (proven-safe size range).
#define S_   4096
#define XROW 259

typedef const float* fpp;
typedef __attribute__((ext_vector_type(8))) short   s8b;   // 8 bf16 = 4 VGPR
typedef __attribute__((ext_vector_type(4))) float   f32x4; // MFMA accum

__device__ __forceinline__ float us2f(unsigned short u){ return __uint_as_float(((unsigned)u)<<16); }
__device__ __forceinline__ unsigned short f2bu(float f){
  __hip_bfloat16 h = __float2bfloat16(f);
  return *reinterpret_cast<unsigned short*>(&h);
}
__device__ __forceinline__ float gelu_f(float v){ return 0.5f*v*(1.0f+erff(v*0.70710678118654752f)); }

// ---------- weight prep -> MFMA fragment order ----------
// FO_m[(ct*8+s)*512 + lane*8 + j] = W[s*32+(lane>>4)*8+j][ct*16+(lane&15)]
// m: 0 W_in, 1 Wq-Wk, 2 Wv, 3 Wg1, 4 Wg2, 5 W_out; then Wp2 (K=128: 4 s-steps).
__global__ __launch_bounds__(256) void k_prep(
    fpp W_in, fpp Wq, fpp Wk, fpp Wv, fpp Wg1, fpp Wg2, fpp W_out, fpp Wp2,
    unsigned short* __restrict__ FO)
{
  int bb = blockIdx.x, wv = threadIdx.x>>6, lane = threadIdx.x&63;
  if (bb < 192) {
    int m  = bb >> 5;
    int fi = (bb & 31)*4 + wv;            // 0..127
    int c = fi >> 3, s = fi & 7;
    int col = c*16 + (lane&15);
    int k0  = s*32 + (lane>>4)*8;
    fpp Wm = (m==0)?W_in:(m==2)?Wv:(m==3)?Wg1:(m==4)?Wg2:(m==5)?W_out:Wq;
    s8b v;
#pragma unroll
    for (int j=0;j<8;j++){
      float f = Wm[(size_t)(k0+j)*256 + col];
      if (m==1) f -= Wk[(size_t)(k0+j)*256 + col];
      v[j] = (short)f2bu(f);
    }
    *(s8b*)(FO + (size_t)m*65536 + (size_t)fi*512 + lane*8) = v;
  } else {                                // Wp2: 16 blocks -> 64 frags (16c x 4s)
    int fi = (bb-192)*4 + wv;             // 0..63
    int c = fi >> 2, s = fi & 3;
    int col = c*16 + (lane&15);
    int k0  = s*32 + (lane>>4)*8;         // < 128
    s8b v;
#pragma unroll
    for (int j=0;j<8;j++) v[j] = (short)f2bu(Wp2[(size_t)(k0+j)*256 + col]);
    *(s8b*)(FO + 393216 + (size_t)fi*512 + lane*8) = v;
  }
}

// ---------- kNN: 512 threads, 8-way scan split, stable tie order ----------
__global__ __launch_bounds__(512) void k_knn(fpp x, unsigned short* __restrict__ idxw)
{
  __shared__ float cxa[S_], cya[S_], cza[S_];      // 48 KiB
  int b = blockIdx.x >> 6;
  int rowbase = (blockIdx.x & 63) * 64;
  fpp xb = x + (size_t)b*S_*XROW;
  for (int t = threadIdx.x; t < S_; t += 512) {
    cxa[t] = xb[t*XROW+0];
    cya[t] = xb[t*XROW+1];
    cza[t] = xb[t*XROW+2];
  }
  __syncthreads();
  int lane = threadIdx.x & 63;
  int wave = threadIdx.x >> 6;                     // 0..7
  int s = rowbase + lane;
  float sx = cxa[s], sy = cya[s], sz = cza[s];
  float sq = fmaf(sz, sz, fmaf(sy, sy, sx*sx));
  float bd[8]; int bi[8];
#pragma unroll
  for (int i=0;i<8;i++){ bd[i]=INFINITY; bi[i]=0; }
  int t0 = wave*512;
  for (int t = t0; t < t0+512; ++t) {
    float tx = cxa[t], ty = cya[t], tz = cza[t];   // uniform addr -> LDS broadcast
    float tq = fmaf(tz, tz, fmaf(ty, ty, tx*tx));
    float dt = fmaf(sz, tz, fmaf(sy, ty, sx*tx));
    float d  = sq + tq - 2.0f*dt;
    if (d < bd[7]) {                               // strict < => stable tie order
      float dd=d; int ii=t;
#pragma unroll
      for (int i=0;i<8;i++){
        if (dd < bd[i]) { float tf=bd[i]; bd[i]=dd; dd=tf; int ti=bi[i]; bi[i]=ii; ii=ti; }
      }
    }
  }
  __syncthreads();                                 // reuse cxa/cya as merge scratch
  float* mf = cxa;
  int*   mi = (int*)cya;
  if (wave > 0) {
#pragma unroll
    for (int i=0;i<8;i++){ mf[((wave-1)*64+lane)*8+i]=bd[i]; mi[((wave-1)*64+lane)*8+i]=bi[i]; }
  }
  __syncthreads();
  if (wave == 0) {
    for (int w=0; w<7; ++w){                       // ascending t-range keeps stability
#pragma unroll
      for (int i=0;i<8;i++){
        float d = mf[(w*64+lane)*8+i]; int tt = mi[(w*64+lane)*8+i];
        if (d < bd[7]) {
          float dd=d; int ii=tt;
#pragma unroll
          for (int q=0;q<8;q++){
            if (dd < bd[q]) { float tf=bd[q]; bd[q]=dd; dd=tf; int ti=bi[q]; bi[q]=ii; ii=ti; }
          }
        }
      }
    }
#pragma unroll
    for (int i=0;i<8;i++) idxw[((size_t)(b*S_ + s))*8 + i] = (unsigned short)bi[i];
  }
}

// ---------- MFMA GEMM phase: 16 tokens x 256 cols, K=256 ----------
// A: LDS bf16, row stride 264. B: fragment-ordered global weights.
// Wave handles cols [ctb*16, ctb*16+64). acc[i] = D-tile for coltile ctb+i.
__device__ __forceinline__ void mfma_phase(const unsigned short* A,
                                           const unsigned short* __restrict__ FOm,
                                           int ctb, int lane, f32x4* acc)
{
  const int arow = lane & 15, akb = lane >> 4;
  s8b af[8];
#pragma unroll
  for (int s=0;s<8;s++) af[s] = *(const s8b*)(A + arow*264 + s*32 + akb*8);
#pragma unroll
  for (int i=0;i<4;i++) acc[i] = (f32x4){0.f,0.f,0.f,0.f};
#pragma unroll
  for (int s=0;s<8;s++){
#pragma unroll
    for (int i=0;i<4;i++){
      s8b bf = *(const s8b*)(FOm + ((size_t)(ctb+i)*8 + s)*512 + lane*8);
      acc[i] = __builtin_amdgcn_mfma_f32_16x16x32_bf16(af[s], bf, acc[i], 0,0,0);
    }
  }
}

// ---------- megakernel: posMLP(MFMA layer2) + 6 MFMA GEMMs + softmax ----------
__global__ __launch_bounds__(256,4) void k_mega(
    fpp x, const unsigned short* __restrict__ idxw,
    fpp Wp1, fpp bp1, fpp bp2,
    const unsigned short* __restrict__ FO,
    fpp b_in, fpp bg1, fpp bg2, fpp b_out,
    float* __restrict__ out)
{
  __shared__ __align__(16) char pool[25344];       // X0|X1|X2  union  hh|w1f|b1f
  __shared__ __align__(16) unsigned short pe[4224];// 16 x 264 bf16
  unsigned short* X0 = (unsigned short*)pool;      // 16 x 264 bf16 each
  unsigned short* X1 = X0 + 4224;
  unsigned short* X2 = X1 + 4224;
  unsigned short (*hh)[136] = (unsigned short (*)[136])pool;  // 64x136 (17408 B)
  float* w1f = (float*)(pool + 17408);             // 10x128
  float* b1f = w1f + 1280;                         // 128

  const int tid = threadIdx.x, lane = tid & 63, wv = tid >> 6;
  const int ctb = wv*4;
  const int arow = lane & 15, akb = lane >> 4, rbase = akb*4;
  const int tok0 = blockIdx.x * 16, b = tok0 >> 12;
  const unsigned short* FO2 = FO + 393216;

  for (int i = tid; i < 1280; i += 256) w1f[i] = Wp1[i];
  if (tid < 128) b1f[tid] = bp1[tid];
  float bp2v[4];
#pragma unroll
  for (int i=0;i<4;i++) bp2v[i] = bp2[(ctb+i)*16 + arow];
  __syncthreads();

  // ---- posMLP: 2 chunks x (64 rows = 8 tok x 8 nb) ----
  for (int c = 0; c < 2; ++c) {
    { // layer 1 (VALU): 4 threads/row x 32 cols
      int r = tid >> 2, q = tid & 3;
      int mtok = c*8 + (r >> 3), kn = r & 7;
      size_t grow = (size_t)(tok0 + mtok), xrow = grow * XROW;
      float cx=x[xrow], cy=x[xrow+1], cz=x[xrow+2];
      int nb = idxw[grow*8 + kn];
      size_t nrow = ((size_t)(b*S_ + nb)) * XROW;
      float nx=x[nrow], ny=x[nrow+1], nz=x[nrow+2];
      float rx=nx-cx, ry=ny-cy, rz=nz-cz;
      float nrm = sqrtf(fmaf(rz,rz,fmaf(ry,ry,rx*rx)));
      float ps[10] = {cx,cy,cz,nx,ny,nz,rx,ry,rz,nrm};
      for (int cc=0; cc<32; ++cc) {
        int col = cc*4 + q;
        float a = b1f[col];
#pragma unroll
        for (int d2=0; d2<10; ++d2) a = fmaf(ps[d2], w1f[d2*128+col], a);
        hh[r][col] = f2bu(gelu_f(a));
      }
    }
    __syncthreads();
    { // layer 2 (MFMA, K=128) + in-register max over 8 neighbors
      for (int rt=0; rt<4; ++rt) {
        s8b af[4];
#pragma unroll
        for (int s=0;s<4;s++) af[s] = *(const s8b*)(&hh[rt*16+arow][s*32 + akb*8]);
        f32x4 acc[4];
#pragma unroll
        for (int i=0;i<4;i++) acc[i] = (f32x4){0.f,0.f,0.f,0.f};
#pragma unroll
        for (int s=0;s<4;s++){
#pragma unroll
          for (int i=0;i<4;i++){
            s8b bf = *(const s8b*)(FO2 + ((size_t)(ctb+i)*4 + s)*512 + lane*8);
            acc[i] = __builtin_amdgcn_mfma_f32_16x16x32_bf16(af[s], bf, acc[i], 0,0,0);
          }
        }
        // rows rt*16 + akb*4 + r; token = row>>3 (const per lane), nb = row&7
#pragma unroll
        for (int i=0;i<4;i++){
          float pm = fmaxf(fmaxf(acc[i][0],acc[i][1]), fmaxf(acc[i][2],acc[i][3]));
          pm = fmaxf(pm, __shfl_xor(pm, 16));      // combine nb halves (akb 0<->1, 2<->3)
          if ((akb & 1) == 0) {
            int tokl = rt*2 + (akb >> 1);
            pe[(c*8 + tokl)*264 + (ctb+i)*16 + arow] = f2bu(pm + bp2v[i]);
          }
        }
      }
    }
    __syncthreads();                               // hh reused next chunk / X0 after
  }

  // ---- stage pre -> X0 (bf16) ----
  for (int i = tid; i < 4096; i += 256) {
    int r = i >> 8, cc = i & 255;
    X0[r*264 + cc] = f2bu(x[(size_t)(tok0 + r)*XROW + 3 + cc]);
  }
  __syncthreads();

  f32x4 acc[4];

  // ---- h = pre @ W_in + b_in + pe -> X1 ----
  mfma_phase(X0, FO, ctb, lane, acc);
#pragma unroll
  for (int i=0;i<4;i++){
    int col = (ctb+i)*16 + arow;
    float bi = b_in[col];
#pragma unroll
    for (int r=0;r<4;r++)
      X1[(rbase+r)*264 + col] = f2bu(acc[i][r] + bi + us2f(pe[(rbase+r)*264 + col]));
  }
  __syncthreads();

  // ---- g = h @ (Wq-Wk) -> X0 ----
  mfma_phase(X1, FO + 65536, ctb, lane, acc);
#pragma unroll
  for (int i=0;i<4;i++){
    int col = (ctb+i)*16 + arow;
#pragma unroll
    for (int r=0;r<4;r++) X0[(rbase+r)*264 + col] = f2bu(acc[i][r]);
  }
  __syncthreads();

  // ---- a1 = gelu(g @ Wg1 + bg1) -> X2 ----
  mfma_phase(X0, FO + 196608, ctb, lane, acc);
#pragma unroll
  for (int i=0;i<4;i++){
    int col = (ctb+i)*16 + arow;
    float bi = bg1[col];
#pragma unroll
    for (int r=0;r<4;r++) X2[(rbase+r)*264 + col] = f2bu(gelu_f(acc[i][r] + bi));
  }
  __syncthreads();

  // ---- a2 = (a1 @ Wg2 + bg2) * 256^-0.5 -> X0 ----
  mfma_phase(X2, FO + 262144, ctb, lane, acc);
#pragma unroll
  for (int i=0;i<4;i++){
    int col = (ctb+i)*16 + arow;
    float bi = bg2[col];
#pragma unroll
    for (int r=0;r<4;r++) X0[(rbase+r)*264 + col] = f2bu((acc[i][r] + bi) * 0.0625f);
  }
  __syncthreads();

  // ---- softmax over 256 channels, X0 in place (16 threads/row x 16 cols) ----
  {
    int row = wv*4 + akb, li = arow;
    unsigned short* rp = X0 + row*264 + li*16;
    uint4 u0 = *(uint4*)rp, u1 = *(uint4*)(rp + 8);
    float f[16];
    f[0]=us2f(u0.x&0xffff); f[1]=us2f(u0.x>>16); f[2]=us2f(u0.y&0xffff); f[3]=us2f(u0.y>>16);
    f[4]=us2f(u0.z&0xffff); f[5]=us2f(u0.z>>16); f[6]=us2f(u0.w&0xffff); f[7]=us2f(u0.w>>16);
    f[8]=us2f(u1.x&0xffff); f[9]=us2f(u1.x>>16); f[10]=us2f(u1.y&0xffff); f[11]=us2f(u1.y>>16);
    f[12]=us2f(u1.z&0xffff); f[13]=us2f(u1.z>>16); f[14]=us2f(u1.w&0xffff); f[15]=us2f(u1.w>>16);
    float mx = f[0];
#pragma unroll
    for (int i=1;i<16;i++) mx = fmaxf(mx, f[i]);
#pragma unroll
    for (int o=1;o<16;o<<=1) mx = fmaxf(mx, __shfl_xor(mx, o));
    float ssum = 0.f;
#pragma unroll
    for (int i=0;i<16;i++){ f[i] = expf(f[i]-mx); ssum += f[i]; }
#pragma unroll
    for (int o=1;o<16;o<<=1) ssum += __shfl_xor(ssum, o);
    float inv = 1.0f/ssum;
    uint4 w0, w1;
    w0.x=f2bu(f[0]*inv) | ((unsigned)f2bu(f[1]*inv)<<16);
    w0.y=f2bu(f[2]*inv) | ((unsigned)f2bu(f[3]*inv)<<16);
    w0.z=f2bu(f[4]*inv) | ((unsigned)f2bu(f[5]*inv)<<16);
    w0.w=f2bu(f[6]*inv) | ((unsigned)f2bu(f[7]*inv)<<16);
    w1.x=f2bu(f[8]*inv) | ((unsigned)f2bu(f[9]*inv)<<16);
    w1.y=f2bu(f[10]*inv)| ((unsigned)f2bu(f[11]*inv)<<16);
    w1.z=f2bu(f[12]*inv)| ((unsigned)f2bu(f[13]*inv)<<16);
    w1.w=f2bu(f[14]*inv)| ((unsigned)f2bu(f[15]*inv)<<16);
    *(uint4*)rp = w0; *(uint4*)(rp+8) = w1;
  }
  __syncthreads();

  // ---- v = h @ Wv ; r = attn * v -> X2 ----
  mfma_phase(X1, FO + 131072, ctb, lane, acc);
#pragma unroll
  for (int i=0;i<4;i++){
    int col = (ctb+i)*16 + arow;
#pragma unroll
    for (int r=0;r<4;r++)
      X2[(rbase+r)*264 + col] = f2bu(us2f(X0[(rbase+r)*264 + col]) * acc[i][r]);
  }
  __syncthreads();

  // ---- out = r @ W_out + b_out + pre (fp32 store) ----
  mfma_phase(X2, FO + 327680, ctb, lane, acc);
#pragma unroll
  for (int i=0;i<4;i++){
    int col = (ctb+i)*16 + arow;
    float bo = b_out[col];
#pragma unroll
    for (int r=0;r<4;r++){
      size_t row = (size_t)(tok0 + rbase + r);
      out[row*256 + col] = acc[i][r] + bo + x[row*XROW + 3 + col];
    }
  }
}

extern "C" void kernel_launch(void* const* d_in, const int* in_sizes, int n_in,
                              void* d_out, int out_size, void* d_ws, size_t ws_size,
                              hipStream_t stream)
{
  fpp x    = (fpp)d_in[0];
  fpp W_in = (fpp)d_in[1];  fpp b_in = (fpp)d_in[2];
  fpp Wq   = (fpp)d_in[3];  fpp Wk   = (fpp)d_in[4];  fpp Wv = (fpp)d_in[5];
  fpp Wg1  = (fpp)d_in[6];  fpp bg1  = (fpp)d_in[7];
  fpp Wg2  = (fpp)d_in[8];  fpp bg2  = (fpp)d_in[9];
  fpp W_out= (fpp)d_in[10]; fpp b_out= (fpp)d_in[11];
  fpp Wp1  = (fpp)d_in[12]; fpp bp1  = (fpp)d_in[13];
  fpp Wp2  = (fpp)d_in[14]; fpp bp2  = (fpp)d_in[15];

  // ---- workspace: 1,114,112 bytes ----
  char* ws = (char*)d_ws;
  unsigned short* idxw = (unsigned short*)ws;            // 131072 u16 = 262144 B
  unsigned short* FO   = (unsigned short*)(ws + 262144); // (6*65536 + 32768) u16 = 851968 B

  k_prep<<<208, 256, 0, stream>>>(W_in,Wq,Wk,Wv,Wg1,Wg2,W_out,Wp2, FO);
  k_knn <<<256, 512, 0, stream>>>(x, idxw);
  k_mega<<<1024,256, 0, stream>>>(x, idxw, Wp1, bp1, bp2, FO,
                                  b_in, bg1, bg2, b_out, (float*)d_out);
}

// Round 6
// 225.217 us; speedup vs baseline: 4.0220x; 1.5547x over previous
//
#include <hip/hip_runtime.h>
#include <hip/hip_bf16.h>
#include <math.h>

// B=4, S=4096, D=256, T=256, K_PATCH=8. fp32 I/O, bf16 MFMA compute, fp32 accum.
// ws = 1.06 MB (proven safe).
#define S_   4096
#define XROW 259

typedef const float* fpp;
typedef __attribute__((ext_vector_type(8))) short   s8b;   // 8 bf16 = 4 VGPR
typedef __attribute__((ext_vector_type(4))) float   f32x4; // MFMA accum

__device__ __forceinline__ float us2f(unsigned short u){ return __uint_as_float(((unsigned)u)<<16); }
__device__ __forceinline__ unsigned short f2bu(float f){
  __hip_bfloat16 h = __float2bfloat16(f);
  return *reinterpret_cast<unsigned short*>(&h);
}
__device__ __forceinline__ float gelu_f(float v){ return 0.5f*v*(1.0f+erff(v*0.70710678118654752f)); }

// ---------- weight prep -> MFMA fragment order ----------
// FO_m[(ct*8+s)*512 + lane*8 + j] = W[s*32+(lane>>4)*8+j][ct*16+(lane&15)]
__global__ __launch_bounds__(256) void k_prep(
    fpp W_in, fpp Wq, fpp Wk, fpp Wv, fpp Wg1, fpp Wg2, fpp W_out, fpp Wp2,
    unsigned short* __restrict__ FO)
{
  int bb = blockIdx.x, wv = threadIdx.x>>6, lane = threadIdx.x&63;
  if (bb < 192) {
    int m  = bb >> 5;
    int fi = (bb & 31)*4 + wv;            // 0..127
    int c = fi >> 3, s = fi & 7;
    int col = c*16 + (lane&15);
    int k0  = s*32 + (lane>>4)*8;
    fpp Wm = (m==0)?W_in:(m==2)?Wv:(m==3)?Wg1:(m==4)?Wg2:(m==5)?W_out:Wq;
    s8b v;
#pragma unroll
    for (int j=0;j<8;j++){
      float f = Wm[(size_t)(k0+j)*256 + col];
      if (m==1) f -= Wk[(size_t)(k0+j)*256 + col];
      v[j] = (short)f2bu(f);
    }
    *(s8b*)(FO + (size_t)m*65536 + (size_t)fi*512 + lane*8) = v;
  } else {                                // Wp2: 16 blocks -> 64 frags (16c x 4s)
    int fi = (bb-192)*4 + wv;             // 0..63
    int c = fi >> 2, s = fi & 3;
    int col = c*16 + (lane&15);
    int k0  = s*32 + (lane>>4)*8;         // < 128
    s8b v;
#pragma unroll
    for (int j=0;j<8;j++) v[j] = (short)f2bu(Wp2[(size_t)(k0+j)*256 + col]);
    *(s8b*)(FO + 393216 + (size_t)fi*512 + lane*8) = v;
  }
}

// ---------- kNN v2: 1024 blocks, 16 rows/block, 16 lanes/row ----------
// Per lane: depth-5 sorted top list over 256 strided candidates; then 8
// extraction rounds per 16-lane group with exact (d, idx) tie-break.
__global__ __launch_bounds__(256) void k_knn(fpp x, unsigned short* __restrict__ idxw)
{
  __shared__ float cxa[S_], cya[S_], cza[S_];      // 48 KiB
  const int rowbase = blockIdx.x * 16;             // global row base (0..16383)
  const int b = rowbase >> 12;
  fpp xb = x + (size_t)b*S_*XROW;
  for (int t = threadIdx.x; t < S_; t += 256) {
    cxa[t] = xb[t*XROW+0];
    cya[t] = xb[t*XROW+1];
    cza[t] = xb[t*XROW+2];
  }
  __syncthreads();
  const int r = threadIdx.x >> 4;                  // row in block (0..15)
  const int L = threadIdx.x & 15;                  // lane in row group
  const int s = (rowbase & (S_-1)) + r;            // row within batch
  float sx = cxa[s], sy = cya[s], sz = cza[s];
  float sq = fmaf(sz, sz, fmaf(sy, sy, sx*sx));
  float bd[5]; int bi[5];
#pragma unroll
  for (int i=0;i<5;i++){ bd[i]=INFINITY; bi[i]=0x7fffffff; }
  for (int i = 0; i < 256; ++i) {
    int t = i*16 + L;                              // ascending t per lane (stable)
    float tx = cxa[t], ty = cya[t], tz = cza[t];   // 16 consec addrs -> conflict-free
    float tq = fmaf(tz, tz, fmaf(ty, ty, tx*tx));
    float dt = fmaf(sz, tz, fmaf(sy, ty, sx*tx));
    float d  = sq + tq - 2.0f*dt;                  // identical formula to ref path
    if (d < bd[4]) {                               // strict < => stable within lane
      float dd=d; int ii=t;
#pragma unroll
      for (int q=0;q<5;q++){
        if (dd < bd[q]) { float tf=bd[q]; bd[q]=dd; dd=tf; int ti=bi[q]; bi[q]=ii; ii=ti; }
      }
    }
  }
  // ---- extraction: 8 rounds of 16-lane tournament, (d, idx) lexicographic ----
  size_t obase = (size_t)(rowbase + r) * 8;
  int h = 0;
#pragma unroll
  for (int round = 0; round < 8; ++round) {
    float mdv = (h==0)?bd[0]:(h==1)?bd[1]:(h==2)?bd[2]:(h==3)?bd[3]:(h==4)?bd[4]:INFINITY;
    int   miv = (h==0)?bi[0]:(h==1)?bi[1]:(h==2)?bi[2]:(h==3)?bi[3]:(h==4)?bi[4]:0x7fffffff;
    float gd = mdv; int gi = miv;
#pragma unroll
    for (int off=1; off<16; off<<=1) {
      float od = __shfl_xor(gd, off);
      int   oi = __shfl_xor(gi, off);
      bool take = (od < gd) || (od == gd && oi < gi);
      gd = take ? od : gd;
      gi = take ? oi : gi;
    }
    if (L == 0) idxw[obase + round] = (unsigned short)gi;
    h += (mdv == gd && miv == gi) ? 1 : 0;         // unique idx -> exactly one winner
  }
}

// ---------- MFMA GEMM phase: 16 tokens x 256 cols, K=256 ----------
__device__ __forceinline__ void mfma_phase(const unsigned short* A,
                                           const unsigned short* __restrict__ FOm,
                                           int ctb, int lane, f32x4* acc)
{
  const int arow = lane & 15, akb = lane >> 4;
  s8b af[8];
#pragma unroll
  for (int s=0;s<8;s++) af[s] = *(const s8b*)(A + arow*264 + s*32 + akb*8);
#pragma unroll
  for (int i=0;i<4;i++) acc[i] = (f32x4){0.f,0.f,0.f,0.f};
#pragma unroll
  for (int s=0;s<8;s++){
#pragma unroll
    for (int i=0;i<4;i++){
      s8b bf = *(const s8b*)(FOm + ((size_t)(ctb+i)*8 + s)*512 + lane*8);
      acc[i] = __builtin_amdgcn_mfma_f32_16x16x32_bf16(af[s], bf, acc[i], 0,0,0);
    }
  }
}

// ---------- megakernel: posMLP(MFMA layer2) + 6 MFMA GEMMs + softmax ----------
__global__ __launch_bounds__(256,4) void k_mega(
    fpp x, const unsigned short* __restrict__ idxw,
    fpp Wp1, fpp bp1, fpp bp2,
    const unsigned short* __restrict__ FO,
    fpp b_in, fpp bg1, fpp bg2, fpp b_out,
    float* __restrict__ out)
{
  __shared__ __align__(16) char pool[25344];       // X0|X1|X2  union  hh|w1f|b1f
  __shared__ __align__(16) unsigned short pe[4224];// 16 x 264 bf16
  unsigned short* X0 = (unsigned short*)pool;      // 16 x 264 bf16 each
  unsigned short* X1 = X0 + 4224;
  unsigned short* X2 = X1 + 4224;
  unsigned short (*hh)[136] = (unsigned short (*)[136])pool;  // 64x136 (17408 B)
  float* w1f = (float*)(pool + 17408);             // 10x128
  float* b1f = w1f + 1280;                         // 128

  const int tid = threadIdx.x, lane = tid & 63, wv = tid >> 6;
  const int ctb = wv*4;
  const int arow = lane & 15, akb = lane >> 4, rbase = akb*4;
  const int tok0 = blockIdx.x * 16, b = tok0 >> 12;
  const unsigned short* FO2 = FO + 393216;

  for (int i = tid; i < 1280; i += 256) w1f[i] = Wp1[i];
  if (tid < 128) b1f[tid] = bp1[tid];
  float bp2v[4];
#pragma unroll
  for (int i=0;i<4;i++) bp2v[i] = bp2[(ctb+i)*16 + arow];
  __syncthreads();

  // ---- posMLP: 2 chunks x (64 rows = 8 tok x 8 nb) ----
  for (int c = 0; c < 2; ++c) {
    { // layer 1 (VALU): 4 threads/row x 32 cols
      int r = tid >> 2, q = tid & 3;
      int mtok = c*8 + (r >> 3), kn = r & 7;
      size_t grow = (size_t)(tok0 + mtok), xrow = grow * XROW;
      float cx=x[xrow], cy=x[xrow+1], cz=x[xrow+2];
      int nb = idxw[grow*8 + kn];
      size_t nrow = ((size_t)(b*S_ + nb)) * XROW;
      float nx=x[nrow], ny=x[nrow+1], nz=x[nrow+2];
      float rx=nx-cx, ry=ny-cy, rz=nz-cz;
      float nrm = sqrtf(fmaf(rz,rz,fmaf(ry,ry,rx*rx)));
      float ps[10] = {cx,cy,cz,nx,ny,nz,rx,ry,rz,nrm};
      for (int cc=0; cc<32; ++cc) {
        int col = cc*4 + q;
        float a = b1f[col];
#pragma unroll
        for (int d2=0; d2<10; ++d2) a = fmaf(ps[d2], w1f[d2*128+col], a);
        hh[r][col] = f2bu(gelu_f(a));
      }
    }
    __syncthreads();
    { // layer 2 (MFMA, K=128) + in-register max over 8 neighbors
      for (int rt=0; rt<4; ++rt) {
        s8b af[4];
#pragma unroll
        for (int s=0;s<4;s++) af[s] = *(const s8b*)(&hh[rt*16+arow][s*32 + akb*8]);
        f32x4 acc[4];
#pragma unroll
        for (int i=0;i<4;i++) acc[i] = (f32x4){0.f,0.f,0.f,0.f};
#pragma unroll
        for (int s=0;s<4;s++){
#pragma unroll
          for (int i=0;i<4;i++){
            s8b bf = *(const s8b*)(FO2 + ((size_t)(ctb+i)*4 + s)*512 + lane*8);
            acc[i] = __builtin_amdgcn_mfma_f32_16x16x32_bf16(af[s], bf, acc[i], 0,0,0);
          }
        }
#pragma unroll
        for (int i=0;i<4;i++){
          float pm = fmaxf(fmaxf(acc[i][0],acc[i][1]), fmaxf(acc[i][2],acc[i][3]));
          pm = fmaxf(pm, __shfl_xor(pm, 16));      // combine nb halves
          if ((akb & 1) == 0) {
            int tokl = rt*2 + (akb >> 1);
            pe[(c*8 + tokl)*264 + (ctb+i)*16 + arow] = f2bu(pm + bp2v[i]);
          }
        }
      }
    }
    __syncthreads();
  }

  // ---- stage pre -> X0 (bf16) ----
  for (int i = tid; i < 4096; i += 256) {
    int r = i >> 8, cc = i & 255;
    X0[r*264 + cc] = f2bu(x[(size_t)(tok0 + r)*XROW + 3 + cc]);
  }
  __syncthreads();

  f32x4 acc[4];

  // ---- h = pre @ W_in + b_in + pe -> X1 ----
  mfma_phase(X0, FO, ctb, lane, acc);
#pragma unroll
  for (int i=0;i<4;i++){
    int col = (ctb+i)*16 + arow;
    float bi = b_in[col];
#pragma unroll
    for (int r=0;r<4;r++)
      X1[(rbase+r)*264 + col] = f2bu(acc[i][r] + bi + us2f(pe[(rbase+r)*264 + col]));
  }
  __syncthreads();

  // ---- g = h @ (Wq-Wk) -> X0 ----
  mfma_phase(X1, FO + 65536, ctb, lane, acc);
#pragma unroll
  for (int i=0;i<4;i++){
    int col = (ctb+i)*16 + arow;
#pragma unroll
    for (int r=0;r<4;r++) X0[(rbase+r)*264 + col] = f2bu(acc[i][r]);
  }
  __syncthreads();

  // ---- a1 = gelu(g @ Wg1 + bg1) -> X2 ----
  mfma_phase(X0, FO + 196608, ctb, lane, acc);
#pragma unroll
  for (int i=0;i<4;i++){
    int col = (ctb+i)*16 + arow;
    float bi = bg1[col];
#pragma unroll
    for (int r=0;r<4;r++) X2[(rbase+r)*264 + col] = f2bu(gelu_f(acc[i][r] + bi));
  }
  __syncthreads();

  // ---- a2 = (a1 @ Wg2 + bg2) * 256^-0.5 -> X0 ----
  mfma_phase(X2, FO + 262144, ctb, lane, acc);
#pragma unroll
  for (int i=0;i<4;i++){
    int col = (ctb+i)*16 + arow;
    float bi = bg2[col];
#pragma unroll
    for (int r=0;r<4;r++) X0[(rbase+r)*264 + col] = f2bu((acc[i][r] + bi) * 0.0625f);
  }
  __syncthreads();

  // ---- softmax over 256 channels, X0 in place ----
  {
    int row = wv*4 + akb, li = arow;
    unsigned short* rp = X0 + row*264 + li*16;
    uint4 u0 = *(uint4*)rp, u1 = *(uint4*)(rp + 8);
    float f[16];
    f[0]=us2f(u0.x&0xffff); f[1]=us2f(u0.x>>16); f[2]=us2f(u0.y&0xffff); f[3]=us2f(u0.y>>16);
    f[4]=us2f(u0.z&0xffff); f[5]=us2f(u0.z>>16); f[6]=us2f(u0.w&0xffff); f[7]=us2f(u0.w>>16);
    f[8]=us2f(u1.x&0xffff); f[9]=us2f(u1.x>>16); f[10]=us2f(u1.y&0xffff); f[11]=us2f(u1.y>>16);
    f[12]=us2f(u1.z&0xffff); f[13]=us2f(u1.z>>16); f[14]=us2f(u1.w&0xffff); f[15]=us2f(u1.w>>16);
    float mx = f[0];
#pragma unroll
    for (int i=1;i<16;i++) mx = fmaxf(mx, f[i]);
#pragma unroll
    for (int o=1;o<16;o<<=1) mx = fmaxf(mx, __shfl_xor(mx, o));
    float ssum = 0.f;
#pragma unroll
    for (int i=0;i<16;i++){ f[i] = expf(f[i]-mx); ssum += f[i]; }
#pragma unroll
    for (int o=1;o<16;o<<=1) ssum += __shfl_xor(ssum, o);
    float inv = 1.0f/ssum;
    uint4 w0, w1;
    w0.x=f2bu(f[0]*inv) | ((unsigned)f2bu(f[1]*inv)<<16);
    w0.y=f2bu(f[2]*inv) | ((unsigned)f2bu(f[3]*inv)<<16);
    w0.z=f2bu(f[4]*inv) | ((unsigned)f2bu(f[5]*inv)<<16);
    w0.w=f2bu(f[6]*inv) | ((unsigned)f2bu(f[7]*inv)<<16);
    w1.x=f2bu(f[8]*inv) | ((unsigned)f2bu(f[9]*inv)<<16);
    w1.y=f2bu(f[10]*inv)| ((unsigned)f2bu(f[11]*inv)<<16);
    w1.z=f2bu(f[12]*inv)| ((unsigned)f2bu(f[13]*inv)<<16);
    w1.w=f2bu(f[14]*inv)| ((unsigned)f2bu(f[15]*inv)<<16);
    *(uint4*)rp = w0; *(uint4*)(rp+8) = w1;
  }
  __syncthreads();

  // ---- v = h @ Wv ; r = attn * v -> X2 ----
  mfma_phase(X1, FO + 131072, ctb, lane, acc);
#pragma unroll
  for (int i=0;i<4;i++){
    int col = (ctb+i)*16 + arow;
#pragma unroll
    for (int r=0;r<4;r++)
      X2[(rbase+r)*264 + col] = f2bu(us2f(X0[(rbase+r)*264 + col]) * acc[i][r]);
  }
  __syncthreads();

  // ---- out = r @ W_out + b_out + pre (fp32 store) ----
  mfma_phase(X2, FO + 327680, ctb, lane, acc);
#pragma unroll
  for (int i=0;i<4;i++){
    int col = (ctb+i)*16 + arow;
    float bo = b_out[col];
#pragma unroll
    for (int r=0;r<4;r++){
      size_t row = (size_t)(tok0 + rbase + r);
      out[row*256 + col] = acc[i][r] + bo + x[row*XROW + 3 + col];
    }
  }
}

extern "C" void kernel_launch(void* const* d_in, const int* in_sizes, int n_in,
                              void* d_out, int out_size, void* d_ws, size_t ws_size,
                              hipStream_t stream)
{
  fpp x    = (fpp)d_in[0];
  fpp W_in = (fpp)d_in[1];  fpp b_in = (fpp)d_in[2];
  fpp Wq   = (fpp)d_in[3];  fpp Wk   = (fpp)d_in[4];  fpp Wv = (fpp)d_in[5];
  fpp Wg1  = (fpp)d_in[6];  fpp bg1  = (fpp)d_in[7];
  fpp Wg2  = (fpp)d_in[8];  fpp bg2  = (fpp)d_in[9];
  fpp W_out= (fpp)d_in[10]; fpp b_out= (fpp)d_in[11];
  fpp Wp1  = (fpp)d_in[12]; fpp bp1  = (fpp)d_in[13];
  fpp Wp2  = (fpp)d_in[14]; fpp bp2  = (fpp)d_in[15];

  // ---- workspace: 1,114,112 bytes ----
  char* ws = (char*)d_ws;
  unsigned short* idxw = (unsigned short*)ws;            // 131072 u16 = 262144 B
  unsigned short* FO   = (unsigned short*)(ws + 262144); // (6*65536 + 32768) u16 = 851968 B

  k_prep<<<208, 256, 0, stream>>>(W_in,Wq,Wk,Wv,Wg1,Wg2,W_out,Wp2, FO);
  k_knn <<<1024,256, 0, stream>>>(x, idxw);
  k_mega<<<1024,256, 0, stream>>>(x, idxw, Wp1, bp1, bp2, FO,
                                  b_in, bg1, bg2, b_out, (float*)d_out);
}

// Round 7
// 116.942 us; speedup vs baseline: 7.7458x; 1.9259x over previous
//
#include <hip/hip_runtime.h>
#include <hip/hip_bf16.h>
#include <math.h>

// B=4, S=4096, D=256, T=256, K_PATCH=8. fp32 I/O, bf16 MFMA compute, fp32 accum.
// ws = 1.06 MB (proven safe).
#define S_   4096
#define XROW 259

typedef const float* fpp;
typedef __attribute__((ext_vector_type(8))) short   s8b;   // 8 bf16 = 4 VGPR
typedef __attribute__((ext_vector_type(4))) float   f32x4; // MFMA accum

__device__ __forceinline__ float us2f(unsigned short u){ return __uint_as_float(((unsigned)u)<<16); }
__device__ __forceinline__ unsigned short f2bu(float f){
  __hip_bfloat16 h = __float2bfloat16(f);
  return *reinterpret_cast<unsigned short*>(&h);
}
__device__ __forceinline__ float gelu_f(float v){ return 0.5f*v*(1.0f+erff(v*0.70710678118654752f)); }

// ---------- weight prep -> MFMA fragment order ----------
// FO_m[(ct*8+s)*512 + lane*8 + j] = W[s*32+(lane>>4)*8+j][ct*16+(lane&15)]
__global__ __launch_bounds__(256) void k_prep(
    fpp W_in, fpp Wq, fpp Wk, fpp Wv, fpp Wg1, fpp Wg2, fpp W_out, fpp Wp2,
    unsigned short* __restrict__ FO)
{
  int bb = blockIdx.x, wv = threadIdx.x>>6, lane = threadIdx.x&63;
  if (bb < 192) {
    int m  = bb >> 5;
    int fi = (bb & 31)*4 + wv;            // 0..127
    int c = fi >> 3, s = fi & 7;
    int col = c*16 + (lane&15);
    int k0  = s*32 + (lane>>4)*8;
    fpp Wm = (m==0)?W_in:(m==2)?Wv:(m==3)?Wg1:(m==4)?Wg2:(m==5)?W_out:Wq;
    s8b v;
#pragma unroll
    for (int j=0;j<8;j++){
      float f = Wm[(size_t)(k0+j)*256 + col];
      if (m==1) f -= Wk[(size_t)(k0+j)*256 + col];
      v[j] = (short)f2bu(f);
    }
    *(s8b*)(FO + (size_t)m*65536 + (size_t)fi*512 + lane*8) = v;
  } else {                                // Wp2: 16 blocks -> 64 frags (16c x 4s)
    int fi = (bb-192)*4 + wv;             // 0..63
    int c = fi >> 2, s = fi & 3;
    int col = c*16 + (lane&15);
    int k0  = s*32 + (lane>>4)*8;         // < 128
    s8b v;
#pragma unroll
    for (int j=0;j<8;j++) v[j] = (short)f2bu(Wp2[(size_t)(k0+j)*256 + col]);
    *(s8b*)(FO + 393216 + (size_t)fi*512 + lane*8) = v;
  }
}

// ---------- kNN v3: packed u32 keys, branchless insert ----------
// 1024 blocks, 16 rows/block, 16 lanes/row, 256 candidates/lane.
// key = (float_bits(d) & 0xFFFFF000) | idx  -- set-membership of top-8 is all
// that matters downstream (max-pool over neighbors), so 11-bit-mantissa
// quantized distance + idx tiebreak is sufficient.
__global__ __launch_bounds__(256) void k_knn(fpp x, unsigned short* __restrict__ idxw)
{
  __shared__ float4 cent4[S_];                     // 64 KiB: (x,y,z,|c|^2)
  const int rowbase = blockIdx.x * 16;
  const int b = rowbase >> 12;
  fpp xb = x + (size_t)b*S_*XROW;
  for (int t = threadIdx.x; t < S_; t += 256) {
    float cx = xb[t*XROW+0], cy = xb[t*XROW+1], cz = xb[t*XROW+2];
    cent4[t] = make_float4(cx, cy, cz, fmaf(cz,cz,fmaf(cy,cy,cx*cx)));
  }
  __syncthreads();
  const int r = threadIdx.x >> 4;                  // row in block
  const int L = threadIdx.x & 15;                  // lane in row group
  const int s = (rowbase & (S_-1)) + r;
  float4 cs = cent4[s];
  const float sx = cs.x, sy = cs.y, sz = cs.z, sq = cs.w;
  unsigned bk0=0xFFFFFFFFu, bk1=0xFFFFFFFFu, bk2=0xFFFFFFFFu,
           bk3=0xFFFFFFFFu, bk4=0xFFFFFFFFu;
  int t = L;
#pragma unroll 4
  for (int i = 0; i < 256; ++i) {
    float4 c = cent4[t];                           // groups broadcast; 2-way in-group = free
    float dt = fmaf(sx,c.x, fmaf(sy,c.y, sz*c.z));
    float d  = fmaxf(sq + fmaf(-2.0f, dt, c.w), 0.0f);
    unsigned kk = (__float_as_uint(d) & 0xFFFFF000u) | (unsigned)t;
    unsigned lo;
    lo = min(kk,bk0); kk = max(kk,bk0); bk0 = lo;  // branchless sorted insert
    lo = min(kk,bk1); kk = max(kk,bk1); bk1 = lo;
    lo = min(kk,bk2); kk = max(kk,bk2); bk2 = lo;
    lo = min(kk,bk3); kk = max(kk,bk3); bk3 = lo;
    bk4 = min(kk,bk4);
    t += 16;
  }
  // ---- extraction: 8 rounds of 16-lane min tournament ----
  size_t obase = (size_t)(rowbase + r) * 8;
  int h = 0;
#pragma unroll
  for (int round = 0; round < 8; ++round) {
    unsigned mdv = (h==0)?bk0:(h==1)?bk1:(h==2)?bk2:(h==3)?bk3:(h==4)?bk4:0xFFFFFFFFu;
    unsigned gd = mdv;
#pragma unroll
    for (int off=1; off<16; off<<=1)
      gd = min(gd, (unsigned)__shfl_xor((int)gd, off));
    if (L == 0) idxw[obase + round] = (unsigned short)(gd & 0xFFFu);
    h += (mdv == gd) ? 1 : 0;                      // keys unique (idx bits)
  }
}

// ---------- MFMA GEMM phase: 16 tokens x 256 cols, K=256 ----------
__device__ __forceinline__ void mfma_phase(const unsigned short* A,
                                           const unsigned short* __restrict__ FOm,
                                           int ctb, int lane, f32x4* acc)
{
  const int arow = lane & 15, akb = lane >> 4;
  s8b af[8];
#pragma unroll
  for (int s=0;s<8;s++) af[s] = *(const s8b*)(A + arow*264 + s*32 + akb*8);
#pragma unroll
  for (int i=0;i<4;i++) acc[i] = (f32x4){0.f,0.f,0.f,0.f};
#pragma unroll
  for (int s=0;s<8;s++){
#pragma unroll
    for (int i=0;i<4;i++){
      s8b bf = *(const s8b*)(FOm + ((size_t)(ctb+i)*8 + s)*512 + lane*8);
      acc[i] = __builtin_amdgcn_mfma_f32_16x16x32_bf16(af[s], bf, acc[i], 0,0,0);
    }
  }
}

// ---------- megakernel: posMLP(MFMA layer2) + 6 MFMA GEMMs + softmax ----------
__global__ __launch_bounds__(256,4) void k_mega(
    fpp x, const unsigned short* __restrict__ idxw,
    fpp Wp1, fpp bp1, fpp bp2,
    const unsigned short* __restrict__ FO,
    fpp b_in, fpp bg1, fpp bg2, fpp b_out,
    float* __restrict__ out)
{
  __shared__ __align__(16) char pool[25344];       // X0|X1|X2  union  hh|w1f|b1f
  __shared__ __align__(16) unsigned short pe[4224];// 16 x 264 bf16
  unsigned short* X0 = (unsigned short*)pool;      // 16 x 264 bf16 each
  unsigned short* X1 = X0 + 4224;
  unsigned short* X2 = X1 + 4224;
  unsigned short (*hh)[136] = (unsigned short (*)[136])pool;  // 64x136 (17408 B)
  float* w1f = (float*)(pool + 17408);             // 10x128
  float* b1f = w1f + 1280;                         // 128

  const int tid = threadIdx.x, lane = tid & 63, wv = tid >> 6;
  const int ctb = wv*4;
  const int arow = lane & 15, akb = lane >> 4, rbase = akb*4;
  const int tok0 = blockIdx.x * 16, b = tok0 >> 12;
  const unsigned short* FO2 = FO + 393216;

  for (int i = tid; i < 1280; i += 256) w1f[i] = Wp1[i];
  if (tid < 128) b1f[tid] = bp1[tid];
  float bp2v[4];
#pragma unroll
  for (int i=0;i<4;i++) bp2v[i] = bp2[(ctb+i)*16 + arow];
  __syncthreads();

  // ---- posMLP: 2 chunks x (64 rows = 8 tok x 8 nb) ----
  for (int c = 0; c < 2; ++c) {
    { // layer 1 (VALU): 4 threads/row x 32 cols
      int r = tid >> 2, q = tid & 3;
      int mtok = c*8 + (r >> 3), kn = r & 7;
      size_t grow = (size_t)(tok0 + mtok), xrow = grow * XROW;
      float cx=x[xrow], cy=x[xrow+1], cz=x[xrow+2];
      int nb = idxw[grow*8 + kn];
      size_t nrow = ((size_t)(b*S_ + nb)) * XROW;
      float nx=x[nrow], ny=x[nrow+1], nz=x[nrow+2];
      float rx=nx-cx, ry=ny-cy, rz=nz-cz;
      float nrm = sqrtf(fmaf(rz,rz,fmaf(ry,ry,rx*rx)));
      float ps[10] = {cx,cy,cz,nx,ny,nz,rx,ry,rz,nrm};
      for (int cc=0; cc<32; ++cc) {
        int col = cc*4 + q;
        float a = b1f[col];
#pragma unroll
        for (int d2=0; d2<10; ++d2) a = fmaf(ps[d2], w1f[d2*128+col], a);
        hh[r][col] = f2bu(gelu_f(a));
      }
    }
    __syncthreads();
    { // layer 2 (MFMA, K=128) + in-register max over 8 neighbors
      for (int rt=0; rt<4; ++rt) {
        s8b af[4];
#pragma unroll
        for (int s=0;s<4;s++) af[s] = *(const s8b*)(&hh[rt*16+arow][s*32 + akb*8]);
        f32x4 acc[4];
#pragma unroll
        for (int i=0;i<4;i++) acc[i] = (f32x4){0.f,0.f,0.f,0.f};
#pragma unroll
        for (int s=0;s<4;s++){
#pragma unroll
          for (int i=0;i<4;i++){
            s8b bf = *(const s8b*)(FO2 + ((size_t)(ctb+i)*4 + s)*512 + lane*8);
            acc[i] = __builtin_amdgcn_mfma_f32_16x16x32_bf16(af[s], bf, acc[i], 0,0,0);
          }
        }
#pragma unroll
        for (int i=0;i<4;i++){
          float pm = fmaxf(fmaxf(acc[i][0],acc[i][1]), fmaxf(acc[i][2],acc[i][3]));
          pm = fmaxf(pm, __shfl_xor(pm, 16));      // combine nb halves
          if ((akb & 1) == 0) {
            int tokl = rt*2 + (akb >> 1);
            pe[(c*8 + tokl)*264 + (ctb+i)*16 + arow] = f2bu(pm + bp2v[i]);
          }
        }
      }
    }
    __syncthreads();
  }

  // ---- stage pre -> X0 (bf16) ----
  for (int i = tid; i < 4096; i += 256) {
    int r = i >> 8, cc = i & 255;
    X0[r*264 + cc] = f2bu(x[(size_t)(tok0 + r)*XROW + 3 + cc]);
  }
  __syncthreads();

  f32x4 acc[4];

  // ---- h = pre @ W_in + b_in + pe -> X1 ----
  mfma_phase(X0, FO, ctb, lane, acc);
#pragma unroll
  for (int i=0;i<4;i++){
    int col = (ctb+i)*16 + arow;
    float bi = b_in[col];
#pragma unroll
    for (int r=0;r<4;r++)
      X1[(rbase+r)*264 + col] = f2bu(acc[i][r] + bi + us2f(pe[(rbase+r)*264 + col]));
  }
  __syncthreads();

  // ---- g = h @ (Wq-Wk) -> X0 ----
  mfma_phase(X1, FO + 65536, ctb, lane, acc);
#pragma unroll
  for (int i=0;i<4;i++){
    int col = (ctb+i)*16 + arow;
#pragma unroll
    for (int r=0;r<4;r++) X0[(rbase+r)*264 + col] = f2bu(acc[i][r]);
  }
  __syncthreads();

  // ---- a1 = gelu(g @ Wg1 + bg1) -> X2 ----
  mfma_phase(X0, FO + 196608, ctb, lane, acc);
#pragma unroll
  for (int i=0;i<4;i++){
    int col = (ctb+i)*16 + arow;
    float bi = bg1[col];
#pragma unroll
    for (int r=0;r<4;r++) X2[(rbase+r)*264 + col] = f2bu(gelu_f(acc[i][r] + bi));
  }
  __syncthreads();

  // ---- a2 = (a1 @ Wg2 + bg2) * 256^-0.5 -> X0 ----
  mfma_phase(X2, FO + 262144, ctb, lane, acc);
#pragma unroll
  for (int i=0;i<4;i++){
    int col = (ctb+i)*16 + arow;
    float bi = bg2[col];
#pragma unroll
    for (int r=0;r<4;r++) X0[(rbase+r)*264 + col] = f2bu((acc[i][r] + bi) * 0.0625f);
  }
  __syncthreads();

  // ---- softmax over 256 channels, X0 in place ----
  {
    int row = wv*4 + akb, li = arow;
    unsigned short* rp = X0 + row*264 + li*16;
    uint4 u0 = *(uint4*)rp, u1 = *(uint4*)(rp + 8);
    float f[16];
    f[0]=us2f(u0.x&0xffff); f[1]=us2f(u0.x>>16); f[2]=us2f(u0.y&0xffff); f[3]=us2f(u0.y>>16);
    f[4]=us2f(u0.z&0xffff); f[5]=us2f(u0.z>>16); f[6]=us2f(u0.w&0xffff); f[7]=us2f(u0.w>>16);
    f[8]=us2f(u1.x&0xffff); f[9]=us2f(u1.x>>16); f[10]=us2f(u1.y&0xffff); f[11]=us2f(u1.y>>16);
    f[12]=us2f(u1.z&0xffff); f[13]=us2f(u1.z>>16); f[14]=us2f(u1.w&0xffff); f[15]=us2f(u1.w>>16);
    float mx = f[0];
#pragma unroll
    for (int i=1;i<16;i++) mx = fmaxf(mx, f[i]);
#pragma unroll
    for (int o=1;o<16;o<<=1) mx = fmaxf(mx, __shfl_xor(mx, o));
    float ssum = 0.f;
#pragma unroll
    for (int i=0;i<16;i++){ f[i] = expf(f[i]-mx); ssum += f[i]; }
#pragma unroll
    for (int o=1;o<16;o<<=1) ssum += __shfl_xor(ssum, o);
    float inv = 1.0f/ssum;
    uint4 w0, w1;
    w0.x=f2bu(f[0]*inv) | ((unsigned)f2bu(f[1]*inv)<<16);
    w0.y=f2bu(f[2]*inv) | ((unsigned)f2bu(f[3]*inv)<<16);
    w0.z=f2bu(f[4]*inv) | ((unsigned)f2bu(f[5]*inv)<<16);
    w0.w=f2bu(f[6]*inv) | ((unsigned)f2bu(f[7]*inv)<<16);
    w1.x=f2bu(f[8]*inv) | ((unsigned)f2bu(f[9]*inv)<<16);
    w1.y=f2bu(f[10]*inv)| ((unsigned)f2bu(f[11]*inv)<<16);
    w1.z=f2bu(f[12]*inv)| ((unsigned)f2bu(f[13]*inv)<<16);
    w1.w=f2bu(f[14]*inv)| ((unsigned)f2bu(f[15]*inv)<<16);
    *(uint4*)rp = w0; *(uint4*)(rp+8) = w1;
  }
  __syncthreads();

  // ---- v = h @ Wv ; r = attn * v -> X2 ----
  mfma_phase(X1, FO + 131072, ctb, lane, acc);
#pragma unroll
  for (int i=0;i<4;i++){
    int col = (ctb+i)*16 + arow;
#pragma unroll
    for (int r=0;r<4;r++)
      X2[(rbase+r)*264 + col] = f2bu(us2f(X0[(rbase+r)*264 + col]) * acc[i][r]);
  }
  __syncthreads();

  // ---- out = r @ W_out + b_out + pre (fp32 store) ----
  mfma_phase(X2, FO + 327680, ctb, lane, acc);
#pragma unroll
  for (int i=0;i<4;i++){
    int col = (ctb+i)*16 + arow;
    float bo = b_out[col];
#pragma unroll
    for (int r=0;r<4;r++){
      size_t row = (size_t)(tok0 + rbase + r);
      out[row*256 + col] = acc[i][r] + bo + x[row*XROW + 3 + col];
    }
  }
}

extern "C" void kernel_launch(void* const* d_in, const int* in_sizes, int n_in,
                              void* d_out, int out_size, void* d_ws, size_t ws_size,
                              hipStream_t stream)
{
  fpp x    = (fpp)d_in[0];
  fpp W_in = (fpp)d_in[1];  fpp b_in = (fpp)d_in[2];
  fpp Wq   = (fpp)d_in[3];  fpp Wk   = (fpp)d_in[4];  fpp Wv = (fpp)d_in[5];
  fpp Wg1  = (fpp)d_in[6];  fpp bg1  = (fpp)d_in[7];
  fpp Wg2  = (fpp)d_in[8];  fpp bg2  = (fpp)d_in[9];
  fpp W_out= (fpp)d_in[10]; fpp b_out= (fpp)d_in[11];
  fpp Wp1  = (fpp)d_in[12]; fpp bp1  = (fpp)d_in[13];
  fpp Wp2  = (fpp)d_in[14]; fpp bp2  = (fpp)d_in[15];

  // ---- workspace: 1,114,112 bytes ----
  char* ws = (char*)d_ws;
  unsigned short* idxw = (unsigned short*)ws;            // 131072 u16 = 262144 B
  unsigned short* FO   = (unsigned short*)(ws + 262144); // (6*65536 + 32768) u16 = 851968 B

  k_prep<<<208, 256, 0, stream>>>(W_in,Wq,Wk,Wv,Wg1,Wg2,W_out,Wp2, FO);
  k_knn <<<1024,256, 0, stream>>>(x, idxw);
  k_mega<<<1024,256, 0, stream>>>(x, idxw, Wp1, bp1, bp2, FO,
                                  b_in, bg1, bg2, b_out, (float*)d_out);
}

// Round 8
// 92.363 us; speedup vs baseline: 9.8070x; 1.2661x over previous
//
#include <hip/hip_runtime.h>
#include <hip/hip_bf16.h>
#include <math.h>

// B=4, S=4096, D=256, T=256, K_PATCH=8. fp32 I/O, bf16 MFMA compute, fp32 accum.
// ws = 1.07 MB; d_out tail doubles as centroid scratch (overwritten by k_mega).
#define S_   4096
#define XROW 259

typedef const float* fpp;
typedef __attribute__((ext_vector_type(8))) short   s8b;   // 8 bf16 = 4 VGPR
typedef __attribute__((ext_vector_type(4))) float   f32x4; // MFMA accum

__device__ __forceinline__ float us2f(unsigned short u){ return __uint_as_float(((unsigned)u)<<16); }
__device__ __forceinline__ unsigned short f2bu(float f){
  __hip_bfloat16 h = __float2bfloat16(f);
  return *reinterpret_cast<unsigned short*>(&h);
}
// sigmoid-form tanh-GELU: 0.5v(1+tanh(c1(v+c2 v^3))) = v*sigma(2u); max abs err ~3e-4
__device__ __forceinline__ float gelu_f(float v){
  float u2 = 2.0f * v * fmaf(0.0356774081f, v*v, 0.7978845608f);
  float e  = __expf(u2);
  return v * (1.0f - __builtin_amdgcn_rcpf(e + 1.0f));
}

// ---------- weight prep -> MFMA fragment order ----------
// FO_m[(ct*8+s)*512 + lane*8 + j] = W[s*32+(lane>>4)*8+j][ct*16+(lane&15)]
// m: 0 W_in, 1 Wq-Wk, 2 Wv, 3 Wg1, 4 Wg2, 5 W_out; FO2 = Wp2 (K=128); FO3 = Wp1 (K=10 pad 32)
__global__ __launch_bounds__(256) void k_prep(
    fpp W_in, fpp Wq, fpp Wk, fpp Wv, fpp Wg1, fpp Wg2, fpp W_out, fpp Wp2, fpp Wp1,
    unsigned short* __restrict__ FO)
{
  int bb = blockIdx.x, wv = threadIdx.x>>6, lane = threadIdx.x&63;
  if (bb < 192) {
    int m  = bb >> 5;
    int fi = (bb & 31)*4 + wv;            // 0..127
    int c = fi >> 3, s = fi & 7;
    int col = c*16 + (lane&15);
    int k0  = s*32 + (lane>>4)*8;
    fpp Wm = (m==0)?W_in:(m==2)?Wv:(m==3)?Wg1:(m==4)?Wg2:(m==5)?W_out:Wq;
    s8b v;
#pragma unroll
    for (int j=0;j<8;j++){
      float f = Wm[(size_t)(k0+j)*256 + col];
      if (m==1) f -= Wk[(size_t)(k0+j)*256 + col];
      v[j] = (short)f2bu(f);
    }
    *(s8b*)(FO + (size_t)m*65536 + (size_t)fi*512 + lane*8) = v;
  } else if (bb < 208) {                  // Wp2: 16 blocks -> 64 frags (16c x 4s)
    int fi = (bb-192)*4 + wv;             // 0..63
    int c = fi >> 2, s = fi & 3;
    int col = c*16 + (lane&15);
    int k0  = s*32 + (lane>>4)*8;         // < 128
    s8b v;
#pragma unroll
    for (int j=0;j<8;j++) v[j] = (short)f2bu(Wp2[(size_t)(k0+j)*256 + col]);
    *(s8b*)(FO + 393216 + (size_t)fi*512 + lane*8) = v;
  } else {                                // Wp1 (10,128) K-padded to 32: 8 frags
    int fi = (bb-208)*4 + wv;             // 0..7
    int col = fi*16 + (lane&15);          // < 128
    int k0  = (lane>>4)*8;
    s8b v;
#pragma unroll
    for (int j=0;j<8;j++){
      int k = k0 + j;
      v[j] = (k < 10) ? (short)f2bu(Wp1[(size_t)k*128 + col]) : (short)0;
    }
    *(s8b*)(FO + 425984 + (size_t)fi*512 + lane*8) = v;
  }
}

// ---------- centroid pack: (x,y,z,|c|^2) float4, coalesced source for k_knn ----------
__global__ __launch_bounds__(256) void k_cent(fpp x, float4* __restrict__ cbuf)
{
  int t = blockIdx.x*256 + threadIdx.x;             // 0..16383
  size_t xrow = (size_t)t * XROW;
  float cx = x[xrow], cy = x[xrow+1], cz = x[xrow+2];
  cbuf[t] = make_float4(cx, cy, cz, fmaf(cz,cz,fmaf(cy,cy,cx*cx)));
}

// ---------- kNN v3: packed u32 keys, branchless insert ----------
__global__ __launch_bounds__(256) void k_knn(const float4* __restrict__ cbuf,
                                             unsigned short* __restrict__ idxw)
{
  __shared__ float4 cent4[S_];                     // 64 KiB
  const int rowbase = blockIdx.x * 16;
  const int b = rowbase >> 12;
  const float4* cb = cbuf + (size_t)b*S_;
  for (int t = threadIdx.x; t < S_; t += 256) cent4[t] = cb[t];   // coalesced 16B/lane
  __syncthreads();
  const int r = threadIdx.x >> 4;
  const int L = threadIdx.x & 15;
  const int s = (rowbase & (S_-1)) + r;
  float4 cs = cent4[s];
  const float sx = cs.x, sy = cs.y, sz = cs.z, sq = cs.w;
  unsigned bk0=0xFFFFFFFFu, bk1=0xFFFFFFFFu, bk2=0xFFFFFFFFu,
           bk3=0xFFFFFFFFu, bk4=0xFFFFFFFFu;
  int t = L;
#pragma unroll 4
  for (int i = 0; i < 256; ++i) {
    float4 c = cent4[t];
    float dt = fmaf(sx,c.x, fmaf(sy,c.y, sz*c.z));
    float d  = fmaxf(sq + fmaf(-2.0f, dt, c.w), 0.0f);
    unsigned kk = (__float_as_uint(d) & 0xFFFFF000u) | (unsigned)t;
    unsigned lo;
    lo = min(kk,bk0); kk = max(kk,bk0); bk0 = lo;
    lo = min(kk,bk1); kk = max(kk,bk1); bk1 = lo;
    lo = min(kk,bk2); kk = max(kk,bk2); bk2 = lo;
    lo = min(kk,bk3); kk = max(kk,bk3); bk3 = lo;
    bk4 = min(kk,bk4);
    t += 16;
  }
  size_t obase = (size_t)(rowbase + r) * 8;
  int h = 0;
#pragma unroll
  for (int round = 0; round < 8; ++round) {
    unsigned mdv = (h==0)?bk0:(h==1)?bk1:(h==2)?bk2:(h==3)?bk3:(h==4)?bk4:0xFFFFFFFFu;
    unsigned gd = mdv;
#pragma unroll
    for (int off=1; off<16; off<<=1)
      gd = min(gd, (unsigned)__shfl_xor((int)gd, off));
    if (L == 0) idxw[obase + round] = (unsigned short)(gd & 0xFFFu);
    h += (mdv == gd) ? 1 : 0;
  }
}

// ---------- megakernel v2: 32 tokens/block, 512 threads (8 waves x 2 col-tiles) ----------
__global__ __launch_bounds__(512,4) void k_mega(
    fpp x, const unsigned short* __restrict__ idxw,
    fpp bp1, fpp bp2,
    const unsigned short* __restrict__ FO,
    fpp b_in, fpp bg1, fpp bg2, fpp b_out,
    float* __restrict__ out)
{
  __shared__ __align__(16) char pool[50688];        // X0|X1|X2  union  psb|hh
  __shared__ __align__(16) unsigned short pe[8448]; // 32 x 264
  unsigned short* X0 = (unsigned short*)pool;       // 32x264 each (16896 B)
  unsigned short* X1 = X0 + 8448;
  unsigned short* X2 = X1 + 8448;
  unsigned short (*psb)[40]  = (unsigned short (*)[40])pool;           // 256x40 (20480 B)
  unsigned short (*hh)[136]  = (unsigned short (*)[136])(pool + 20480);// 64x136 (17408 B)

  const int tid = threadIdx.x, lane = tid & 63, wv = tid >> 6;   // wv 0..7
  const int arow = lane & 15, akb = lane >> 4, rbase = akb*4;
  const int ctb = wv*2;
  const int tok0 = blockIdx.x * 32, b = tok0 >> 12;
  const unsigned short* FO2 = FO + 393216;
  const unsigned short* FO3 = FO + 425984;
  const int col0 = ctb*16 + arow, col1 = col0 + 16;

  s8b bf3 = *(const s8b*)(FO3 + wv*512 + lane*8);   // w1 fragment, reused all chunks
  float b1v = bp1[wv*16 + arow];
  float bp2v0 = bp2[col0], bp2v1 = bp2[col1];

  // ---- stage pos_struct bf16 for all 256 (token,neighbor) rows ----
  if (tid < 256) {
    int tk = tid >> 3;
    size_t grow = (size_t)(tok0 + tk), xrow = grow * XROW;
    float cx=x[xrow], cy=x[xrow+1], cz=x[xrow+2];
    int nb = idxw[grow*8 + (tid & 7)];
    size_t nrow = ((size_t)(b*S_ + nb)) * XROW;
    float nx=x[nrow], ny=x[nrow+1], nz=x[nrow+2];
    float rx=nx-cx, ry=ny-cy, rz=nz-cz;
    float nrm = sqrtf(fmaf(rz,rz,fmaf(ry,ry,rx*rx)));
    unsigned short* p = psb[tid];
    s8b v0 = { (short)f2bu(cx),(short)f2bu(cy),(short)f2bu(cz),(short)f2bu(nx),
               (short)f2bu(ny),(short)f2bu(nz),(short)f2bu(rx),(short)f2bu(ry) };
    s8b v1 = { (short)f2bu(rz),(short)f2bu(nrm),0,0,0,0,0,0 };
    s8b vz = { 0,0,0,0,0,0,0,0 };
    *(s8b*)(p) = v0; *(s8b*)(p+8) = v1; *(s8b*)(p+16) = vz; *(s8b*)(p+24) = vz;
  }
  __syncthreads();

  // ---- posMLP: 4 chunks x 64 rows; layer1 MFMA (K=32) + gelu -> hh; layer2 MFMA -> pe ----
  for (int c=0;c<4;++c){
    f32x4 h4[4];
#pragma unroll
    for (int rt=0;rt<4;++rt){
      s8b af = *(const s8b*)(&psb[c*64 + rt*16 + arow][akb*8]);
      h4[rt] = __builtin_amdgcn_mfma_f32_16x16x32_bf16(af, bf3, (f32x4){0.f,0.f,0.f,0.f}, 0,0,0);
    }
#pragma unroll
    for (int rt=0;rt<4;++rt)
#pragma unroll
      for (int rr=0;rr<4;++rr)
        hh[rt*16 + rbase + rr][wv*16 + arow] = f2bu(gelu_f(h4[rt][rr] + b1v));
    __syncthreads();
    f32x4 a2c[4][2];
#pragma unroll
    for (int rt=0;rt<4;++rt){ a2c[rt][0]=(f32x4){0.f,0.f,0.f,0.f}; a2c[rt][1]=(f32x4){0.f,0.f,0.f,0.f}; }
#pragma unroll
    for (int s=0;s<4;++s){
      s8b af0 = *(const s8b*)(&hh[ 0 + arow][s*32 + akb*8]);
      s8b af1 = *(const s8b*)(&hh[16 + arow][s*32 + akb*8]);
      s8b af2 = *(const s8b*)(&hh[32 + arow][s*32 + akb*8]);
      s8b af3v= *(const s8b*)(&hh[48 + arow][s*32 + akb*8]);
#pragma unroll
      for (int i=0;i<2;++i){
        s8b bf = *(const s8b*)(FO2 + ((size_t)((ctb+i)*4 + s))*512 + lane*8);
        a2c[0][i] = __builtin_amdgcn_mfma_f32_16x16x32_bf16(af0,  bf, a2c[0][i], 0,0,0);
        a2c[1][i] = __builtin_amdgcn_mfma_f32_16x16x32_bf16(af1,  bf, a2c[1][i], 0,0,0);
        a2c[2][i] = __builtin_amdgcn_mfma_f32_16x16x32_bf16(af2,  bf, a2c[2][i], 0,0,0);
        a2c[3][i] = __builtin_amdgcn_mfma_f32_16x16x32_bf16(af3v, bf, a2c[3][i], 0,0,0);
      }
    }
#pragma unroll
    for (int rt=0;rt<4;++rt)
#pragma unroll
      for (int i=0;i<2;++i){
        float pm = fmaxf(fmaxf(a2c[rt][i][0],a2c[rt][i][1]), fmaxf(a2c[rt][i][2],a2c[rt][i][3]));
        pm = fmaxf(pm, __shfl_xor(pm, 16));       // combine neighbor halves
        if ((akb & 1) == 0)
          pe[(c*8 + rt*2 + (akb>>1))*264 + (ctb+i)*16 + arow] = f2bu(pm + (i ? bp2v1 : bp2v0));
      }
    __syncthreads();
  }

  // ---- stage pre -> X0 (psb/hh dead) ----
#pragma unroll
  for (int p=0;p<16;++p){
    int i = p*512 + tid;
    int row = i >> 8, cc = i & 255;
    X0[row*264 + cc] = f2bu(x[(size_t)(tok0 + row)*XROW + 3 + cc]);
  }
  __syncthreads();

  f32x4 acc[2][2];
  auto gphase = [&](const unsigned short* A, const unsigned short* FOm){
#pragma unroll
    for (int rt=0;rt<2;++rt){ acc[rt][0]=(f32x4){0.f,0.f,0.f,0.f}; acc[rt][1]=(f32x4){0.f,0.f,0.f,0.f}; }
#pragma unroll
    for (int s=0;s<8;++s){
      s8b a0 = *(const s8b*)(A + arow*264 + s*32 + akb*8);
      s8b a1 = *(const s8b*)(A + (16+arow)*264 + s*32 + akb*8);
#pragma unroll
      for (int i=0;i<2;++i){
        s8b bf = *(const s8b*)(FOm + ((size_t)((ctb+i)*8 + s))*512 + lane*8);
        acc[0][i] = __builtin_amdgcn_mfma_f32_16x16x32_bf16(a0, bf, acc[0][i], 0,0,0);
        acc[1][i] = __builtin_amdgcn_mfma_f32_16x16x32_bf16(a1, bf, acc[1][i], 0,0,0);
      }
    }
  };

  // ---- h = pre @ W_in + b_in + pe -> X1 ----
  gphase(X0, FO);
#pragma unroll
  for (int i=0;i<2;++i){
    int col = i ? col1 : col0;
    float bi = b_in[col];
#pragma unroll
    for (int rt=0;rt<2;++rt)
#pragma unroll
      for (int rr=0;rr<4;++rr){
        int row = rt*16 + rbase + rr;
        X1[row*264 + col] = f2bu(acc[rt][i][rr] + bi + us2f(pe[row*264 + col]));
      }
  }
  __syncthreads();

  // ---- g = h @ (Wq-Wk) -> X0 ----
  gphase(X1, FO + 65536);
#pragma unroll
  for (int i=0;i<2;++i){
    int col = i ? col1 : col0;
#pragma unroll
    for (int rt=0;rt<2;++rt)
#pragma unroll
      for (int rr=0;rr<4;++rr)
        X0[(rt*16 + rbase + rr)*264 + col] = f2bu(acc[rt][i][rr]);
  }
  __syncthreads();

  // ---- a1 = gelu(g @ Wg1 + bg1) -> X2 ----
  gphase(X0, FO + 196608);
#pragma unroll
  for (int i=0;i<2;++i){
    int col = i ? col1 : col0;
    float bi = bg1[col];
#pragma unroll
    for (int rt=0;rt<2;++rt)
#pragma unroll
      for (int rr=0;rr<4;++rr)
        X2[(rt*16 + rbase + rr)*264 + col] = f2bu(gelu_f(acc[rt][i][rr] + bi));
  }
  __syncthreads();

  // ---- a2 = (a1 @ Wg2 + bg2) * 256^-0.5 -> X0 ----
  gphase(X2, FO + 262144);
#pragma unroll
  for (int i=0;i<2;++i){
    int col = i ? col1 : col0;
    float bi = bg2[col];
#pragma unroll
    for (int rt=0;rt<2;++rt)
#pragma unroll
      for (int rr=0;rr<4;++rr)
        X0[(rt*16 + rbase + rr)*264 + col] = f2bu((acc[rt][i][rr] + bi) * 0.0625f);
  }
  __syncthreads();

  // ---- softmax over 256 channels, X0 in place (32 rows, 16 lanes/row) ----
  {
    int row = tid >> 4, li = tid & 15;
    unsigned short* rp = X0 + row*264 + li*16;
    uint4 u0 = *(uint4*)rp, u1 = *(uint4*)(rp + 8);
    float f[16];
    f[0]=us2f(u0.x&0xffff); f[1]=us2f(u0.x>>16); f[2]=us2f(u0.y&0xffff); f[3]=us2f(u0.y>>16);
    f[4]=us2f(u0.z&0xffff); f[5]=us2f(u0.z>>16); f[6]=us2f(u0.w&0xffff); f[7]=us2f(u0.w>>16);
    f[8]=us2f(u1.x&0xffff); f[9]=us2f(u1.x>>16); f[10]=us2f(u1.y&0xffff); f[11]=us2f(u1.y>>16);
    f[12]=us2f(u1.z&0xffff); f[13]=us2f(u1.z>>16); f[14]=us2f(u1.w&0xffff); f[15]=us2f(u1.w>>16);
    float mx = f[0];
#pragma unroll
    for (int i=1;i<16;i++) mx = fmaxf(mx, f[i]);
#pragma unroll
    for (int o=1;o<16;o<<=1) mx = fmaxf(mx, __shfl_xor(mx, o));
    float ssum = 0.f;
#pragma unroll
    for (int i=0;i<16;i++){ f[i] = __expf(f[i]-mx); ssum += f[i]; }
#pragma unroll
    for (int o=1;o<16;o<<=1) ssum += __shfl_xor(ssum, o);
    float inv = __builtin_amdgcn_rcpf(ssum);
    uint4 w0, w1;
    w0.x=f2bu(f[0]*inv) | ((unsigned)f2bu(f[1]*inv)<<16);
    w0.y=f2bu(f[2]*inv) | ((unsigned)f2bu(f[3]*inv)<<16);
    w0.z=f2bu(f[4]*inv) | ((unsigned)f2bu(f[5]*inv)<<16);
    w0.w=f2bu(f[6]*inv) | ((unsigned)f2bu(f[7]*inv)<<16);
    w1.x=f2bu(f[8]*inv) | ((unsigned)f2bu(f[9]*inv)<<16);
    w1.y=f2bu(f[10]*inv)| ((unsigned)f2bu(f[11]*inv)<<16);
    w1.z=f2bu(f[12]*inv)| ((unsigned)f2bu(f[13]*inv)<<16);
    w1.w=f2bu(f[14]*inv)| ((unsigned)f2bu(f[15]*inv)<<16);
    *(uint4*)rp = w0; *(uint4*)(rp+8) = w1;
  }
  __syncthreads();

  // ---- v = h @ Wv ; r = attn * v -> X2 ----
  gphase(X1, FO + 131072);
#pragma unroll
  for (int i=0;i<2;++i){
    int col = i ? col1 : col0;
#pragma unroll
    for (int rt=0;rt<2;++rt)
#pragma unroll
      for (int rr=0;rr<4;++rr){
        int row = rt*16 + rbase + rr;
        X2[row*264 + col] = f2bu(us2f(X0[row*264 + col]) * acc[rt][i][rr]);
      }
  }
  __syncthreads();

  // ---- out = r @ W_out + b_out + pre (fp32 store) ----
  gphase(X2, FO + 327680);
#pragma unroll
  for (int i=0;i<2;++i){
    int col = i ? col1 : col0;
    float bo = b_out[col];
#pragma unroll
    for (int rt=0;rt<2;++rt)
#pragma unroll
      for (int rr=0;rr<4;++rr){
        size_t row = (size_t)(tok0 + rt*16 + rbase + rr);
        out[row*256 + col] = acc[rt][i][rr] + bo + x[row*XROW + 3 + col];
      }
  }
}

extern "C" void kernel_launch(void* const* d_in, const int* in_sizes, int n_in,
                              void* d_out, int out_size, void* d_ws, size_t ws_size,
                              hipStream_t stream)
{
  fpp x    = (fpp)d_in[0];
  fpp W_in = (fpp)d_in[1];  fpp b_in = (fpp)d_in[2];
  fpp Wq   = (fpp)d_in[3];  fpp Wk   = (fpp)d_in[4];  fpp Wv = (fpp)d_in[5];
  fpp Wg1  = (fpp)d_in[6];  fpp bg1  = (fpp)d_in[7];
  fpp Wg2  = (fpp)d_in[8];  fpp bg2  = (fpp)d_in[9];
  fpp W_out= (fpp)d_in[10]; fpp b_out= (fpp)d_in[11];
  fpp Wp1  = (fpp)d_in[12]; fpp bp1  = (fpp)d_in[13];
  fpp Wp2  = (fpp)d_in[14]; fpp bp2  = (fpp)d_in[15];

  // ---- workspace: 1,122,304 bytes ----
  char* ws = (char*)d_ws;
  unsigned short* idxw = (unsigned short*)ws;            // 131072 u16 = 262144 B
  unsigned short* FO   = (unsigned short*)(ws + 262144); // 430080 u16 = 860160 B

  // centroid scratch in d_out tail (overwritten by k_mega afterwards)
  float4* cbuf = (float4*)((char*)d_out + 16515072);     // 16384 x 16 B = 262144 B

  k_prep<<<210, 256, 0, stream>>>(W_in,Wq,Wk,Wv,Wg1,Wg2,W_out,Wp2,Wp1, FO);
  k_cent<<<64,  256, 0, stream>>>(x, cbuf);
  k_knn <<<1024,256, 0, stream>>>(cbuf, idxw);
  k_mega<<<512, 512, 0, stream>>>(x, idxw, bp1, bp2, FO,
                                  b_in, bg1, bg2, b_out, (float*)d_out);
}

// Round 9
// 83.297 us; speedup vs baseline: 10.8745x; 1.1088x over previous
//
#include <hip/hip_runtime.h>
#include <hip/hip_bf16.h>
#include <math.h>

// B=4, S=4096, D=256, T=256, K_PATCH=8. fp32 I/O, bf16 MFMA compute, fp32 accum.
// ws = 1.07 MB; d_out tail doubles as centroid scratch (overwritten by k_mega).
#define S_   4096
#define XROW 259
#define XS   280   // u16 row stride, X tiles: 560B = 35*16 (aligned) -> conflict-free A-reads
#define HHS  144   // u16 row stride, hh: 288B = 18*16 -> conflict-free L2 A-reads
#define PES  280   // u16 row stride, pe

typedef const float* fpp;
typedef __attribute__((ext_vector_type(8))) short   s8b;   // 8 bf16 = 4 VGPR
typedef __attribute__((ext_vector_type(4))) float   f32x4; // MFMA accum

__device__ __forceinline__ float us2f(unsigned short u){ return __uint_as_float(((unsigned)u)<<16); }
__device__ __forceinline__ unsigned short f2bu(float f){
  __hip_bfloat16 h = __float2bfloat16(f);
  return *reinterpret_cast<unsigned short*>(&h);
}
// sigmoid-form tanh-GELU, max abs err ~3e-4
__device__ __forceinline__ float gelu_f(float v){
  float u2 = 2.0f * v * fmaf(0.0356774081f, v*v, 0.7978845608f);
  float e  = __expf(u2);
  return v * (1.0f - __builtin_amdgcn_rcpf(e + 1.0f));
}

// ---------- weight prep -> MFMA fragment order; + centroid pack ----------
__global__ __launch_bounds__(256) void k_prep(
    fpp W_in, fpp Wq, fpp Wk, fpp Wv, fpp Wg1, fpp Wg2, fpp W_out, fpp Wp2, fpp Wp1,
    fpp x, unsigned short* __restrict__ FO, float4* __restrict__ cbuf)
{
  int bb = blockIdx.x, wv = threadIdx.x>>6, lane = threadIdx.x&63;
  if (bb < 192) {
    int m  = bb >> 5;
    int fi = (bb & 31)*4 + wv;            // 0..127
    int c = fi >> 3, s = fi & 7;
    int col = c*16 + (lane&15);
    int k0  = s*32 + (lane>>4)*8;
    fpp Wm = (m==0)?W_in:(m==2)?Wv:(m==3)?Wg1:(m==4)?Wg2:(m==5)?W_out:Wq;
    s8b v;
#pragma unroll
    for (int j=0;j<8;j++){
      float f = Wm[(size_t)(k0+j)*256 + col];
      if (m==1) f -= Wk[(size_t)(k0+j)*256 + col];
      v[j] = (short)f2bu(f);
    }
    *(s8b*)(FO + (size_t)m*65536 + (size_t)fi*512 + lane*8) = v;
  } else if (bb < 208) {                  // Wp2 (128,256): 64 frags
    int fi = (bb-192)*4 + wv;
    int c = fi >> 2, s = fi & 3;
    int col = c*16 + (lane&15);
    int k0  = s*32 + (lane>>4)*8;
    s8b v;
#pragma unroll
    for (int j=0;j<8;j++) v[j] = (short)f2bu(Wp2[(size_t)(k0+j)*256 + col]);
    *(s8b*)(FO + 393216 + (size_t)fi*512 + lane*8) = v;
  } else if (bb < 210) {                  // Wp1 (10,128), K-pad 32: 8 frags
    int fi = (bb-208)*4 + wv;
    int col = fi*16 + (lane&15);
    int k0  = (lane>>4)*8;
    s8b v;
#pragma unroll
    for (int j=0;j<8;j++){
      int k = k0 + j;
      v[j] = (k < 10) ? (short)f2bu(Wp1[(size_t)k*128 + col]) : (short)0;
    }
    *(s8b*)(FO + 425984 + (size_t)fi*512 + lane*8) = v;
  } else {                                // centroid pack: (x,y,z,|c|^2 / 2)
    int t = (bb-210)*256 + threadIdx.x;   // 0..16383
    size_t xrow = (size_t)t * XROW;
    float cx = x[xrow], cy = x[xrow+1], cz = x[xrow+2];
    cbuf[t] = make_float4(cx, cy, cz, 0.5f*fmaf(cz,cz,fmaf(cy,cy,cx*cx)));
  }
}

// ---------- kNN v4: 512 blocks x 512 thr (32 rows x 16 lanes), depth-4, folded score ----------
__global__ __launch_bounds__(512,4) void k_knn(const float4* __restrict__ cbuf,
                                               unsigned short* __restrict__ idxw)
{
  __shared__ float4 cent4[S_];                     // 64 KiB
  const int rowbase = blockIdx.x * 32;
  const int b = rowbase >> 12;
  const float4* cb = cbuf + (size_t)b*S_;
  for (int t = threadIdx.x; t < S_; t += 512) cent4[t] = cb[t];
  __syncthreads();
  const int r = threadIdx.x >> 4;                  // 0..31
  const int L = threadIdx.x & 15;
  const int s = (rowbase & (S_-1)) + r;
  float4 cs = cent4[s];
  const float nsx = -cs.x, nsy = -cs.y, nsz = -cs.z;
  // score m = |c|^2/2 - s.c  (ascending with distance); sign-mapped to u32
  unsigned bk0=0xFFFFFFFFu, bk1=0xFFFFFFFFu, bk2=0xFFFFFFFFu, bk3=0xFFFFFFFFu;
  int t = L;
#pragma unroll 4
  for (int i = 0; i < 256; ++i) {
    float4 c = cent4[t];
    float m = fmaf(nsx, c.x, fmaf(nsy, c.y, fmaf(nsz, c.z, c.w)));
    unsigned ub = __float_as_uint(m);
    ub ^= ((unsigned)((int)ub >> 31)) | 0x80000000u;           // order-monotone map
    unsigned kk = (ub & 0xFFFFF000u) | (unsigned)t;
    unsigned lo;
    lo = min(kk,bk0); kk = max(kk,bk0); bk0 = lo;
    lo = min(kk,bk1); kk = max(kk,bk1); bk1 = lo;
    lo = min(kk,bk2); kk = max(kk,bk2); bk2 = lo;
    bk3 = min(kk,bk3);
    t += 16;
  }
  size_t obase = (size_t)(rowbase + r) * 8;
  int h = 0;
#pragma unroll
  for (int round = 0; round < 8; ++round) {
    unsigned mdv = (h==0)?bk0:(h==1)?bk1:(h==2)?bk2:(h==3)?bk3:0xFFFFFFFFu;
    unsigned gd = mdv;
#pragma unroll
    for (int off=1; off<16; off<<=1)
      gd = min(gd, (unsigned)__shfl_xor((int)gd, off));
    if (L == 0) idxw[obase + round] = (unsigned short)(gd & 0xFFFu);
    h += (mdv == gd) ? 1 : 0;
  }
}

// ---------- megakernel v3: 32 tokens/block, 512 thr; conflict-free strides; fused g+v ----------
__global__ __launch_bounds__(512,4) void k_mega(
    fpp x, const unsigned short* __restrict__ idxw,
    fpp bp1, fpp bp2,
    const unsigned short* __restrict__ FO,
    fpp b_in, fpp bg1, fpp bg2, fpp b_out,
    float* __restrict__ out)
{
  __shared__ __align__(16) char pool[53760];        // X0|X1|X2  union  psb|hh
  __shared__ __align__(16) unsigned short pe[8960]; // 32 x 280
  unsigned short* X0 = (unsigned short*)pool;       // 32 x 280 u16 each (17920 B)
  unsigned short* X1 = X0 + 32*XS;
  unsigned short* X2 = X1 + 32*XS;
  unsigned short (*psb)[40] = (unsigned short (*)[40])pool;             // 256x40 (20480 B)
  unsigned short (*hh)[HHS] = (unsigned short (*)[HHS])(pool + 20480);  // 64x144 (18432 B)

  const int tid = threadIdx.x, lane = tid & 63, wv = tid >> 6;   // wv 0..7
  const int arow = lane & 15, akb = lane >> 4, rbase = akb*4;
  const int ctb = wv*2;
  const int tok0 = blockIdx.x * 32, b = tok0 >> 12;
  const unsigned short* FO2 = FO + 393216;
  const unsigned short* FO3 = FO + 425984;
  const int col0 = ctb*16 + arow, col1 = col0 + 16;

  s8b bf3 = *(const s8b*)(FO3 + wv*512 + lane*8);
  float b1v = bp1[wv*16 + arow];
  float bp2v0 = bp2[col0], bp2v1 = bp2[col1];

  // ---- stage pos_struct (256 rows = 32 tok x 8 nb) ----
  if (tid < 256) {
    int tk = tid >> 3;
    size_t grow = (size_t)(tok0 + tk), xrow = grow * XROW;
    float cx=x[xrow], cy=x[xrow+1], cz=x[xrow+2];
    int nb = idxw[grow*8 + (tid & 7)];
    size_t nrow = ((size_t)(b*S_ + nb)) * XROW;
    float nx=x[nrow], ny=x[nrow+1], nz=x[nrow+2];
    float rx=nx-cx, ry=ny-cy, rz=nz-cz;
    float nrm = sqrtf(fmaf(rz,rz,fmaf(ry,ry,rx*rx)));
    unsigned short* p = psb[tid];
    s8b v0 = { (short)f2bu(cx),(short)f2bu(cy),(short)f2bu(cz),(short)f2bu(nx),
               (short)f2bu(ny),(short)f2bu(nz),(short)f2bu(rx),(short)f2bu(ry) };
    s8b v1 = { (short)f2bu(rz),(short)f2bu(nrm),0,0,0,0,0,0 };
    s8b vz = { 0,0,0,0,0,0,0,0 };
    *(s8b*)(p) = v0; *(s8b*)(p+8) = v1; *(s8b*)(p+16) = vz; *(s8b*)(p+24) = vz;
  }
  __syncthreads();

  // ---- posMLP: 4 chunks x 64 rows ----
  for (int c=0;c<4;++c){
    f32x4 h4[4];
#pragma unroll
    for (int rt=0;rt<4;++rt){
      s8b af = *(const s8b*)(&psb[c*64 + rt*16 + arow][akb*8]);
      h4[rt] = __builtin_amdgcn_mfma_f32_16x16x32_bf16(af, bf3, (f32x4){0.f,0.f,0.f,0.f}, 0,0,0);
    }
#pragma unroll
    for (int rt=0;rt<4;++rt)
#pragma unroll
      for (int rr=0;rr<4;++rr)
        hh[rt*16 + rbase + rr][wv*16 + arow] = f2bu(gelu_f(h4[rt][rr] + b1v));
    __syncthreads();
    f32x4 a2c[4][2];
#pragma unroll
    for (int rt=0;rt<4;++rt){ a2c[rt][0]=(f32x4){0.f,0.f,0.f,0.f}; a2c[rt][1]=(f32x4){0.f,0.f,0.f,0.f}; }
#pragma unroll
    for (int s=0;s<4;++s){
      s8b af0 = *(const s8b*)(&hh[ 0 + arow][s*32 + akb*8]);
      s8b af1 = *(const s8b*)(&hh[16 + arow][s*32 + akb*8]);
      s8b af2 = *(const s8b*)(&hh[32 + arow][s*32 + akb*8]);
      s8b af3v= *(const s8b*)(&hh[48 + arow][s*32 + akb*8]);
#pragma unroll
      for (int i=0;i<2;++i){
        s8b bf = *(const s8b*)(FO2 + ((size_t)((ctb+i)*4 + s))*512 + lane*8);
        a2c[0][i] = __builtin_amdgcn_mfma_f32_16x16x32_bf16(af0,  bf, a2c[0][i], 0,0,0);
        a2c[1][i] = __builtin_amdgcn_mfma_f32_16x16x32_bf16(af1,  bf, a2c[1][i], 0,0,0);
        a2c[2][i] = __builtin_amdgcn_mfma_f32_16x16x32_bf16(af2,  bf, a2c[2][i], 0,0,0);
        a2c[3][i] = __builtin_amdgcn_mfma_f32_16x16x32_bf16(af3v, bf, a2c[3][i], 0,0,0);
      }
    }
#pragma unroll
    for (int rt=0;rt<4;++rt)
#pragma unroll
      for (int i=0;i<2;++i){
        float pm = fmaxf(fmaxf(a2c[rt][i][0],a2c[rt][i][1]), fmaxf(a2c[rt][i][2],a2c[rt][i][3]));
        pm = fmaxf(pm, __shfl_xor(pm, 16));
        if ((akb & 1) == 0)
          pe[(c*8 + rt*2 + (akb>>1))*PES + (ctb+i)*16 + arow] = f2bu(pm + (i ? bp2v1 : bp2v0));
      }
    __syncthreads();
  }

  // ---- stage pre -> X0 (b128 writes; psb/hh dead) ----
#pragma unroll
  for (int p=0;p<2;++p){
    int i2 = p*512 + tid;
    int row = i2 >> 5, c = i2 & 31;
    const float* src = x + (size_t)(tok0 + row)*XROW + 3 + c*8;
    s8b v;
#pragma unroll
    for (int j=0;j<8;j++) v[j] = (short)f2bu(src[j]);
    *(s8b*)(X0 + row*XS + c*8) = v;
  }
  __syncthreads();

  f32x4 acc[2][2];
  auto gphase = [&](const unsigned short* A, const unsigned short* FOm){
#pragma unroll
    for (int rt=0;rt<2;++rt){ acc[rt][0]=(f32x4){0.f,0.f,0.f,0.f}; acc[rt][1]=(f32x4){0.f,0.f,0.f,0.f}; }
#pragma unroll
    for (int s=0;s<8;++s){
      s8b a0 = *(const s8b*)(A + arow*XS + s*32 + akb*8);
      s8b a1 = *(const s8b*)(A + (16+arow)*XS + s*32 + akb*8);
#pragma unroll
      for (int i=0;i<2;++i){
        s8b bf = *(const s8b*)(FOm + ((size_t)((ctb+i)*8 + s))*512 + lane*8);
        acc[0][i] = __builtin_amdgcn_mfma_f32_16x16x32_bf16(a0, bf, acc[0][i], 0,0,0);
        acc[1][i] = __builtin_amdgcn_mfma_f32_16x16x32_bf16(a1, bf, acc[1][i], 0,0,0);
      }
    }
  };

  // ---- h = pre @ W_in + b_in + pe -> X1 ----
  gphase(X0, FO);
#pragma unroll
  for (int i=0;i<2;++i){
    int col = i ? col1 : col0;
    float bi = b_in[col];
#pragma unroll
    for (int rt=0;rt<2;++rt)
#pragma unroll
      for (int rr=0;rr<4;++rr){
        int row = rt*16 + rbase + rr;
        X1[row*XS + col] = f2bu(acc[rt][i][rr] + bi + us2f(pe[row*PES + col]));
      }
  }
  __syncthreads();

  // ---- FUSED: g = h@(Wq-Wk) -> X2 ; v = h@Wv -> registers (held to r-phase) ----
  f32x4 accv[2][2];
  {
#pragma unroll
    for (int rt=0;rt<2;++rt){
      acc[rt][0]=(f32x4){0.f,0.f,0.f,0.f};  acc[rt][1]=(f32x4){0.f,0.f,0.f,0.f};
      accv[rt][0]=(f32x4){0.f,0.f,0.f,0.f}; accv[rt][1]=(f32x4){0.f,0.f,0.f,0.f};
    }
#pragma unroll
    for (int s=0;s<8;++s){
      s8b a0 = *(const s8b*)(X1 + arow*XS + s*32 + akb*8);
      s8b a1 = *(const s8b*)(X1 + (16+arow)*XS + s*32 + akb*8);
#pragma unroll
      for (int i=0;i<2;++i){
        s8b bg = *(const s8b*)(FO +  65536 + ((size_t)((ctb+i)*8 + s))*512 + lane*8);
        s8b bv = *(const s8b*)(FO + 131072 + ((size_t)((ctb+i)*8 + s))*512 + lane*8);
        acc[0][i]  = __builtin_amdgcn_mfma_f32_16x16x32_bf16(a0, bg, acc[0][i], 0,0,0);
        acc[1][i]  = __builtin_amdgcn_mfma_f32_16x16x32_bf16(a1, bg, acc[1][i], 0,0,0);
        accv[0][i] = __builtin_amdgcn_mfma_f32_16x16x32_bf16(a0, bv, accv[0][i], 0,0,0);
        accv[1][i] = __builtin_amdgcn_mfma_f32_16x16x32_bf16(a1, bv, accv[1][i], 0,0,0);
      }
    }
#pragma unroll
    for (int i=0;i<2;++i){
      int col = i ? col1 : col0;
#pragma unroll
      for (int rt=0;rt<2;++rt)
#pragma unroll
        for (int rr=0;rr<4;++rr)
          X2[(rt*16 + rbase + rr)*XS + col] = f2bu(acc[rt][i][rr]);
    }
  }
  __syncthreads();

  // ---- a1 = gelu(g @ Wg1 + bg1) -> X0 ----
  gphase(X2, FO + 196608);
#pragma unroll
  for (int i=0;i<2;++i){
    int col = i ? col1 : col0;
    float bi = bg1[col];
#pragma unroll
    for (int rt=0;rt<2;++rt)
#pragma unroll
      for (int rr=0;rr<4;++rr)
        X0[(rt*16 + rbase + rr)*XS + col] = f2bu(gelu_f(acc[rt][i][rr] + bi));
  }
  __syncthreads();

  // ---- a2 = (a1 @ Wg2 + bg2) * 256^-0.5 -> X2 ----
  gphase(X0, FO + 262144);
#pragma unroll
  for (int i=0;i<2;++i){
    int col = i ? col1 : col0;
    float bi = bg2[col];
#pragma unroll
    for (int rt=0;rt<2;++rt)
#pragma unroll
      for (int rr=0;rr<4;++rr)
        X2[(rt*16 + rbase + rr)*XS + col] = f2bu((acc[rt][i][rr] + bi) * 0.0625f);
  }
  __syncthreads();

  // ---- softmax over 256 channels, X2 in place (32 rows, 16 lanes/row) ----
  {
    int row = tid >> 4, li = tid & 15;
    unsigned short* rp = X2 + row*XS + li*16;
    uint4 u0 = *(uint4*)rp, u1 = *(uint4*)(rp + 8);
    float f[16];
    f[0]=us2f(u0.x&0xffff); f[1]=us2f(u0.x>>16); f[2]=us2f(u0.y&0xffff); f[3]=us2f(u0.y>>16);
    f[4]=us2f(u0.z&0xffff); f[5]=us2f(u0.z>>16); f[6]=us2f(u0.w&0xffff); f[7]=us2f(u0.w>>16);
    f[8]=us2f(u1.x&0xffff); f[9]=us2f(u1.x>>16); f[10]=us2f(u1.y&0xffff); f[11]=us2f(u1.y>>16);
    f[12]=us2f(u1.z&0xffff); f[13]=us2f(u1.z>>16); f[14]=us2f(u1.w&0xffff); f[15]=us2f(u1.w>>16);
    float mx = f[0];
#pragma unroll
    for (int i=1;i<16;i++) mx = fmaxf(mx, f[i]);
#pragma unroll
    for (int o=1;o<16;o<<=1) mx = fmaxf(mx, __shfl_xor(mx, o));
    float ssum = 0.f;
#pragma unroll
    for (int i=0;i<16;i++){ f[i] = __expf(f[i]-mx); ssum += f[i]; }
#pragma unroll
    for (int o=1;o<16;o<<=1) ssum += __shfl_xor(ssum, o);
    float inv = __builtin_amdgcn_rcpf(ssum);
    uint4 w0, w1;
    w0.x=f2bu(f[0]*inv) | ((unsigned)f2bu(f[1]*inv)<<16);
    w0.y=f2bu(f[2]*inv) | ((unsigned)f2bu(f[3]*inv)<<16);
    w0.z=f2bu(f[4]*inv) | ((unsigned)f2bu(f[5]*inv)<<16);
    w0.w=f2bu(f[6]*inv) | ((unsigned)f2bu(f[7]*inv)<<16);
    w1.x=f2bu(f[8]*inv) | ((unsigned)f2bu(f[9]*inv)<<16);
    w1.y=f2bu(f[10]*inv)| ((unsigned)f2bu(f[11]*inv)<<16);
    w1.z=f2bu(f[12]*inv)| ((unsigned)f2bu(f[13]*inv)<<16);
    w1.w=f2bu(f[14]*inv)| ((unsigned)f2bu(f[15]*inv)<<16);
    *(uint4*)rp = w0; *(uint4*)(rp+8) = w1;
  }
  __syncthreads();

  // ---- r = attn * v(regs) -> X0 ----
#pragma unroll
  for (int i=0;i<2;++i){
    int col = i ? col1 : col0;
#pragma unroll
    for (int rt=0;rt<2;++rt)
#pragma unroll
      for (int rr=0;rr<4;++rr){
        int row = rt*16 + rbase + rr;
        X0[row*XS + col] = f2bu(us2f(X2[row*XS + col]) * accv[rt][i][rr]);
      }
  }
  __syncthreads();

  // ---- out = r @ W_out + b_out + pre (fp32 store) ----
  gphase(X0, FO + 327680);
#pragma unroll
  for (int i=0;i<2;++i){
    int col = i ? col1 : col0;
    float bo = b_out[col];
#pragma unroll
    for (int rt=0;rt<2;++rt)
#pragma unroll
      for (int rr=0;rr<4;++rr){
        size_t row = (size_t)(tok0 + rt*16 + rbase + rr);
        out[row*256 + col] = acc[rt][i][rr] + bo + x[row*XROW + 3 + col];
      }
  }
}

extern "C" void kernel_launch(void* const* d_in, const int* in_sizes, int n_in,
                              void* d_out, int out_size, void* d_ws, size_t ws_size,
                              hipStream_t stream)
{
  fpp x    = (fpp)d_in[0];
  fpp W_in = (fpp)d_in[1];  fpp b_in = (fpp)d_in[2];
  fpp Wq   = (fpp)d_in[3];  fpp Wk   = (fpp)d_in[4];  fpp Wv = (fpp)d_in[5];
  fpp Wg1  = (fpp)d_in[6];  fpp bg1  = (fpp)d_in[7];
  fpp Wg2  = (fpp)d_in[8];  fpp bg2  = (fpp)d_in[9];
  fpp W_out= (fpp)d_in[10]; fpp b_out= (fpp)d_in[11];
  fpp Wp1  = (fpp)d_in[12]; fpp bp1  = (fpp)d_in[13];
  fpp Wp2  = (fpp)d_in[14]; fpp bp2  = (fpp)d_in[15];

  // ---- workspace: 1,122,304 bytes ----
  char* ws = (char*)d_ws;
  unsigned short* idxw = (unsigned short*)ws;            // 131072 u16 = 262144 B
  unsigned short* FO   = (unsigned short*)(ws + 262144); // 430080 u16 = 860160 B

  // centroid scratch in d_out tail (overwritten by k_mega afterwards)
  float4* cbuf = (float4*)((char*)d_out + 16515072);     // 16384 x 16 B = 262144 B

  k_prep<<<274, 256, 0, stream>>>(W_in,Wq,Wk,Wv,Wg1,Wg2,W_out,Wp2,Wp1, x, FO, cbuf);
  k_knn <<<512, 512, 0, stream>>>(cbuf, idxw);
  k_mega<<<512, 512, 0, stream>>>(x, idxw, bp1, bp2, FO,
                                  b_in, bg1, bg2, b_out, (float*)d_out);
}